// Round 1
// baseline (19994.122 us; speedup 1.0000x reference)
//
#include <hip/hip_runtime.h>

#define T_STEPS 64
#define BATCH   128
#define HID     1024
#define H3      3072
#define EMB     1024
#define SLEN    128

// C[M x N] = A[M x K] (row-major, lda) * W[N x K]^T + bias, optional tanh.
// Tiles: BM=32, BN=64, BK=16; 256 threads; each thread computes 2x4 outputs.
// Rows of A may be indirected through aidx (embedding gather).
__global__ __launch_bounds__(256) void gemm_k(
    const float* __restrict__ A, int lda, const int* __restrict__ aidx,
    const float* __restrict__ W, const float* __restrict__ bias,
    float* __restrict__ C, int ldc, int K, int act)
{
    __shared__ float As[16][32];
    __shared__ float Ws[16][64];
    const int tid = threadIdx.x;
    const int bx = blockIdx.x, by = blockIdx.y;
    const int ty = tid >> 4, tx = tid & 15;

    // loader mapping: each thread loads one float4 of W tile; threads<128 also A tile
    const int lr = tid >> 2;           // 0..63 (tile row)
    const int lk = (tid & 3) << 2;     // 0,4,8,12 (k offset)

    const float* arow = nullptr;
    if (lr < 32) {
        long r = (long)by * 32 + lr;
        long src = aidx ? (long)aidx[r] : r;
        arow = A + src * (long)lda;
    }
    const float* wrow = W + ((long)bx * 64 + lr) * (long)K;

    float acc[2][4];
    #pragma unroll
    for (int i = 0; i < 2; ++i)
        #pragma unroll
        for (int j = 0; j < 4; ++j) acc[i][j] = 0.f;

    for (int k0 = 0; k0 < K; k0 += 16) {
        float4 av = make_float4(0.f, 0.f, 0.f, 0.f);
        if (lr < 32) av = *(const float4*)(arow + k0 + lk);
        float4 wv = *(const float4*)(wrow + k0 + lk);
        __syncthreads();
        if (lr < 32) {
            As[lk + 0][lr] = av.x; As[lk + 1][lr] = av.y;
            As[lk + 2][lr] = av.z; As[lk + 3][lr] = av.w;
        }
        Ws[lk + 0][lr] = wv.x; Ws[lk + 1][lr] = wv.y;
        Ws[lk + 2][lr] = wv.z; Ws[lk + 3][lr] = wv.w;
        __syncthreads();
        #pragma unroll
        for (int kk = 0; kk < 16; ++kk) {
            float a0 = As[kk][ty * 2 + 0];
            float a1 = As[kk][ty * 2 + 1];
            float4 w4 = *(const float4*)&Ws[kk][tx * 4];
            acc[0][0] += a0 * w4.x; acc[0][1] += a0 * w4.y;
            acc[0][2] += a0 * w4.z; acc[0][3] += a0 * w4.w;
            acc[1][0] += a1 * w4.x; acc[1][1] += a1 * w4.y;
            acc[1][2] += a1 * w4.z; acc[1][3] += a1 * w4.w;
        }
    }

    const long crow = (long)by * 32 + ty * 2;
    const int  ccol = bx * 64 + tx * 4;
    #pragma unroll
    for (int i = 0; i < 2; ++i) {
        float4 o;
        o.x = acc[i][0]; o.y = acc[i][1]; o.z = acc[i][2]; o.w = acc[i][3];
        if (bias) {
            o.x += bias[ccol + 0]; o.y += bias[ccol + 1];
            o.z += bias[ccol + 2]; o.w += bias[ccol + 3];
        }
        if (act) {
            o.x = tanhf(o.x); o.y = tanhf(o.y);
            o.z = tanhf(o.z); o.w = tanhf(o.w);
        }
        *(float4*)(C + (crow + i) * (long)ldc + ccol) = o;
    }
}

// h[b][j] = (1-z)*n + z*h ; torch GRUCell gate order r,z,n
__global__ __launch_bounds__(256) void gru_gate(
    const float* __restrict__ gi, const float* __restrict__ gh,
    float* __restrict__ h)
{
    const int idx = blockIdx.x * 256 + threadIdx.x;   // 0 .. B*HID-1
    const int b = idx >> 10;
    const int j = idx & 1023;
    const long base = (long)b * H3 + j;
    const float ir = gi[base],           hr = gh[base];
    const float iz = gi[base + HID],     hz = gh[base + HID];
    const float in_ = gi[base + 2*HID],  hn = gh[base + 2*HID];
    const float r = 1.f / (1.f + __expf(-(ir + hr)));
    const float z = 1.f / (1.f + __expf(-(iz + hz)));
    const float n = tanhf(in_ + r * hn);
    h[idx] = (1.f - z) * n + z * h[idx];
}

// Per-batch attention: scores = H[:,b,:] . q1[b], softmax over S, context,
// writes cc[b] = concat(context, h1[b]).  One block per b, 256 threads.
__global__ __launch_bounds__(256) void attn_k(
    const float* __restrict__ H, const float* __restrict__ q1,
    const float* __restrict__ h1, float* __restrict__ cc)
{
    __shared__ float qs[HID];
    __shared__ float sc[SLEN];
    const int b = blockIdx.x, tid = threadIdx.x;

    ((float4*)qs)[tid] = ((const float4*)(q1 + (long)b * HID))[tid];
    __syncthreads();

    const int wave = tid >> 6, lane = tid & 63;
    for (int si = 0; si < 32; ++si) {
        const int s = wave * 32 + si;
        const float* hrow = H + ((long)s * BATCH + b) * HID;
        float p = 0.f;
        #pragma unroll
        for (int i = 0; i < 4; ++i) {
            const int k = i * 256 + lane * 4;
            float4 hv = *(const float4*)(hrow + k);
            float4 qv = *(const float4*)(qs + k);
            p += hv.x * qv.x + hv.y * qv.y + hv.z * qv.z + hv.w * qv.w;
        }
        #pragma unroll
        for (int off = 32; off > 0; off >>= 1) p += __shfl_down(p, off);
        if (lane == 0) sc[s] = p;
    }
    __syncthreads();

    if (tid < 64) {
        float v0 = sc[tid], v1 = sc[tid + 64];
        float m = fmaxf(v0, v1);
        #pragma unroll
        for (int off = 32; off > 0; off >>= 1) m = fmaxf(m, __shfl_xor(m, off));
        float e0 = __expf(v0 - m), e1 = __expf(v1 - m);
        float se = e0 + e1;
        #pragma unroll
        for (int off = 32; off > 0; off >>= 1) se += __shfl_xor(se, off);
        const float inv = 1.f / se;
        sc[tid] = e0 * inv; sc[tid + 64] = e1 * inv;
    }
    __syncthreads();

    float4 acc = make_float4(0.f, 0.f, 0.f, 0.f);
    const float* hb = H + (long)b * HID + tid * 4;
    for (int s = 0; s < SLEN; ++s) {
        const float a = sc[s];
        float4 hv = *(const float4*)(hb + (long)s * BATCH * HID);
        acc.x += a * hv.x; acc.y += a * hv.y;
        acc.z += a * hv.z; acc.w += a * hv.w;
    }
    float* ccb = cc + (long)b * 2 * HID;
    ((float4*)ccb)[tid] = acc;
    ((float4*)(ccb + HID))[tid] = ((const float4*)(h1 + (long)b * HID))[tid];
}

extern "C" void kernel_launch(void* const* d_in, const int* in_sizes, int n_in,
                              void* d_out, int out_size, void* d_ws, size_t ws_size,
                              hipStream_t stream)
{
    const int*   input = (const int*)  d_in[0];
    const float* h_in  = (const float*)d_in[1];
    const float* Hbuf  = (const float*)d_in[2];
    const float* emb   = (const float*)d_in[3];
    const float* w_ih  = (const float*)d_in[4];
    const float* w_hh  = (const float*)d_in[5];
    const float* b_ih  = (const float*)d_in[6];
    const float* b_hh  = (const float*)d_in[7];
    const float* L1    = (const float*)d_in[8];
    const float* L2    = (const float*)d_in[9];

    float* out = (float*)d_out;                        // (T,B,HID)
    float* hst = out + (long)T_STEPS * BATCH * HID;    // (2,B,HID) live state = h_final
    float* h0  = hst;
    float* h1  = hst + (long)BATCH * HID;

    float* ws     = (float*)d_ws;
    float* gibuf  = ws;                                // 128*3072
    float* ghbuf  = gibuf + (long)BATCH * H3;          // 128*3072
    float* q1buf  = ghbuf + (long)BATCH * H3;          // 128*1024
    float* ccbuf  = q1buf + (long)BATCH * HID;         // 128*2048
    float* gi0all = ccbuf + (long)BATCH * 2 * HID;     // optional: T*128*3072
    const size_t base_f = (size_t)(gi0all - ws);
    const bool pre = ws_size >= (base_f + (size_t)T_STEPS * BATCH * H3) * sizeof(float);

    // live h state in d_out tail; re-init every call (harness poisons d_out)
    hipMemcpyAsync(hst, h_in, 2L * BATCH * HID * sizeof(float),
                   hipMemcpyDeviceToDevice, stream);

    const dim3 blk(256);
    const dim3 g3(H3 / 64, BATCH / 32);    // (48,4)
    const dim3 g1(HID / 64, BATCH / 32);   // (16,4)
    const dim3 gg(BATCH * HID / 256);      // gate kernel

    if (pre) {
        // hoisted layer-0 input GEMM for all T at once: (T*B) x 3H x EMB
        const dim3 gp(H3 / 64, (T_STEPS * BATCH) / 32);  // (48,256)
        gemm_k<<<gp, blk, 0, stream>>>(emb, EMB, input, w_ih, b_ih,
                                       gi0all, H3, EMB, 0);
    }

    for (int t = 0; t < T_STEPS; ++t) {
        const float* gi0 = pre ? (gi0all + (long)t * BATCH * H3) : gibuf;
        if (!pre)
            gemm_k<<<g3, blk, 0, stream>>>(emb, EMB, input + t * BATCH,
                                           w_ih, b_ih, gibuf, H3, EMB, 0);
        // layer 0: gh0 = h0 @ w_hh0^T + b_hh0 ; h0 <- gru(gi0, gh0, h0)
        gemm_k<<<g3, blk, 0, stream>>>(h0, HID, nullptr, w_hh, b_hh,
                                       ghbuf, H3, HID, 0);
        gru_gate<<<gg, blk, 0, stream>>>(gi0, ghbuf, h0);
        // layer 1
        gemm_k<<<g3, blk, 0, stream>>>(h0, HID, nullptr,
                                       w_ih + (long)H3 * EMB, b_ih + H3,
                                       gibuf, H3, HID, 0);
        gemm_k<<<g3, blk, 0, stream>>>(h1, HID, nullptr,
                                       w_hh + (long)H3 * HID, b_hh + H3,
                                       ghbuf, H3, HID, 0);
        gru_gate<<<gg, blk, 0, stream>>>(gibuf, ghbuf, h1);
        // attention
        gemm_k<<<g1, blk, 0, stream>>>(h1, HID, nullptr, L1, nullptr,
                                       q1buf, HID, HID, 0);
        attn_k<<<dim3(BATCH), blk, 0, stream>>>(Hbuf, q1buf, h1, ccbuf);
        // out = tanh(concat(c, h1) @ L2^T)
        gemm_k<<<g1, blk, 0, stream>>>(ccbuf, 2 * HID, nullptr, L2, nullptr,
                                       out + (long)t * BATCH * HID, HID,
                                       2 * HID, 1);
    }
}

// Round 2
// 10703.880 us; speedup vs baseline: 1.8679x; 1.8679x over previous
//
#include <hip/hip_runtime.h>

#define T_STEPS 64
#define BATCH   128
#define HID     1024
#define H3      3072
#define EMBD    1024
#define SLEN    128
#define BH      (BATCH * HID)

typedef __attribute__((ext_vector_type(8))) short short8;
typedef __attribute__((ext_vector_type(4))) float f32x4;

__device__ __forceinline__ unsigned short f2bf(float x) {
    unsigned int u = __float_as_uint(x);
    unsigned int r = (u + 0x7fffu + ((u >> 16) & 1u)) >> 16;
    return (unsigned short)r;
}
__device__ __forceinline__ float bf2f(unsigned short h) {
    return __uint_as_float(((unsigned int)h) << 16);
}
__device__ __forceinline__ unsigned int pk(unsigned short a, unsigned short b) {
    return (unsigned int)a | ((unsigned int)b << 16);
}
// 8 f32 -> hi-plane uint4 + lo-plane uint4 (bf16 pairs, elem order preserved)
__device__ __forceinline__ void cvt8(const float4& x, const float4& y,
                                     uint4& H, uint4& L) {
    unsigned short h0 = f2bf(x.x), h1 = f2bf(x.y), h2 = f2bf(x.z), h3 = f2bf(x.w);
    unsigned short h4 = f2bf(y.x), h5 = f2bf(y.y), h6 = f2bf(y.z), h7 = f2bf(y.w);
    unsigned short l0 = f2bf(x.x - bf2f(h0)), l1 = f2bf(x.y - bf2f(h1));
    unsigned short l2 = f2bf(x.z - bf2f(h2)), l3 = f2bf(x.w - bf2f(h3));
    unsigned short l4 = f2bf(y.x - bf2f(h4)), l5 = f2bf(y.y - bf2f(h5));
    unsigned short l6 = f2bf(y.z - bf2f(h6)), l7 = f2bf(y.w - bf2f(h7));
    H = make_uint4(pk(h0,h1), pk(h2,h3), pk(h4,h5), pk(h6,h7));
    L = make_uint4(pk(l0,l1), pk(l2,l3), pk(l4,l5), pk(l6,l7));
}
__device__ __forceinline__ short8 ld8(const unsigned short* p) {
    return *(const short8*)p;
}
__device__ __forceinline__ float sigf(float x) {
    return 1.f / (1.f + __expf(-x));
}

// C = A(MxK) @ W(NxK)^T (+bias)(+gate epilogue).
// Block: 256 thr (4 waves). BM=64 (4 m-tiles, wave w owns m-tile w).
// BJ=16 (one 16-col j-tile), P parts (3: r/z/n j-major; 1: plain).
// K-chunks of 32; bf16 hi/lo split: 3 MFMAs per tile per chunk.
// MODE 0: store G(+bias)(+tanh). MODE 1: G is h-side (gh), other=gi buf.
// MODE 2: G is i-side (gi), other=gh buf. Gate writes h_new to out.
template<int P, int MODE, bool ACT>
__device__ __forceinline__ void gemm_core(
    const float* __restrict__ A, int lda, const int* __restrict__ aidx,
    const float* __restrict__ W, int K, const float* __restrict__ bias,
    const float* __restrict__ other, const float* __restrict__ hprev,
    float* __restrict__ out, int ldo)
{
    extern __shared__ __align__(16) unsigned short smem[];
    unsigned short* As = smem;            // [2buf][2pl][2048 halfs]
    unsigned short* Ws = smem + 8192;     // [2buf][2pl][P*512 halfs]
    const int tid = threadIdx.x;
    const int w = tid >> 6, l = tid & 63;
    const int g = l >> 4, r16 = l & 15;
    const int bx = blockIdx.x, by = blockIdx.y;

    // ---- staging roles ----
    const int as_row = tid >> 2, as_g = tid & 3;
    const long aR = (long)by * 64 + as_row;
    const float* aptr = (aidx ? A + (size_t)aidx[aR] * lda
                              : A + (size_t)aR * lda) + as_g * 8;
    const int a_slot8 = ((as_row >> 4) * 64 + as_g * 16 + (as_row & 15)) * 8;

    const int WSLOT = P * 64;
    const bool doW = tid >= 256 - WSLOT;
    const float* wptr = nullptr;
    int w_slot8 = 0;
    if (doW) {
        int s = tid - (256 - WSLOT);
        int wrow = s >> 2, wg = s & 3;
        int p = wrow >> 4, jr = wrow & 15;
        int grow = (P == 3 ? p * HID : 0) + bx * 16 + jr;
        wptr = W + (size_t)grow * K + wg * 8;
        w_slot8 = (p * 64 + wg * 16 + jr) * 8;
    }

    f32x4 acc[P];
    #pragma unroll
    for (int p = 0; p < P; ++p) acc[p] = (f32x4)0.f;

    const int NC = K >> 5;
    float4 a0, a1, w0, w1;

    auto LOADC = [&](int c) {
        const float* pa = aptr + c * 32;
        a0 = *(const float4*)pa; a1 = *(const float4*)(pa + 4);
        if (doW) {
            const float* pw = wptr + c * 32;
            w0 = *(const float4*)pw; w1 = *(const float4*)(pw + 4);
        }
    };
    auto CVTW = [&](int c) {
        const int b = c & 1;
        uint4 Hh, Ll;
        cvt8(a0, a1, Hh, Ll);
        *(uint4*)(As + b * 4096 + a_slot8) = Hh;
        *(uint4*)(As + b * 4096 + 2048 + a_slot8) = Ll;
        if (doW) {
            cvt8(w0, w1, Hh, Ll);
            *(uint4*)(Ws + b * (2 * P * 512) + w_slot8) = Hh;
            *(uint4*)(Ws + b * (2 * P * 512) + P * 512 + w_slot8) = Ll;
        }
    };

    LOADC(0);
    CVTW(0);
    LOADC(1);
    __syncthreads();

    for (int c = 0; c < NC; ++c) {
        const int b = c & 1;
        const unsigned short* aB = As + b * 4096 + (w * 64 + l) * 8;
        short8 ah = ld8(aB);
        short8 al = ld8(aB + 2048);
        short8 wh[P], wl[P];
        #pragma unroll
        for (int p = 0; p < P; ++p) {
            const unsigned short* wB = Ws + b * (2 * P * 512) + (p * 64 + l) * 8;
            wh[p] = ld8(wB);
            wl[p] = ld8(wB + P * 512);
        }
        if (c + 1 < NC) CVTW(c + 1);
        if (c + 2 < NC) LOADC(c + 2);
        #pragma unroll
        for (int p = 0; p < P; ++p) {
            acc[p] = __builtin_amdgcn_mfma_f32_16x16x32_bf16(ah, wl[p], acc[p], 0, 0, 0);
            acc[p] = __builtin_amdgcn_mfma_f32_16x16x32_bf16(al, wh[p], acc[p], 0, 0, 0);
            acc[p] = __builtin_amdgcn_mfma_f32_16x16x32_bf16(ah, wh[p], acc[p], 0, 0, 0);
        }
        __syncthreads();
    }

    // ---- epilogue ----
    const int jc = bx * 16 + r16;
    if (MODE == 0) {
        #pragma unroll
        for (int p = 0; p < P; ++p) {
            const int colbase = (P == 3 ? p * HID : 0);
            const float bv = bias ? bias[colbase + jc] : 0.f;
            #pragma unroll
            for (int reg = 0; reg < 4; ++reg) {
                const long R = (long)by * 64 + w * 16 + g * 4 + reg;
                float v = acc[p][reg] + bv;
                if (ACT) v = tanhf(v);
                out[R * (long)ldo + colbase + jc] = v;
            }
        }
    } else {
        const float br = bias[jc], bz = bias[HID + jc], bn = bias[2 * HID + jc];
        #pragma unroll
        for (int reg = 0; reg < 4; ++reg) {
            const long R = (long)by * 64 + w * 16 + g * 4 + reg;
            const float Gr = acc[0][reg] + br;
            const float Gz = acc[1][reg] + bz;
            const float Gn = acc[2][reg] + bn;
            const float* orow = other + R * (long)H3;
            const float o_r = orow[jc], o_z = orow[HID + jc], o_n = orow[2 * HID + jc];
            const float hp = hprev[R * (long)HID + jc];
            float rr, zz, nn;
            if (MODE == 1) {            // G = h-side
                rr = sigf(o_r + Gr); zz = sigf(o_z + Gz);
                nn = tanhf(o_n + rr * Gn);
            } else {                    // G = i-side
                rr = sigf(Gr + o_r); zz = sigf(Gz + o_z);
                nn = tanhf(Gn + rr * o_n);
            }
            out[R * (long)HID + jc] = (1.f - zz) * nn + zz * hp;
        }
    }
}

template<int P, int MODE, bool ACT>
__global__ __launch_bounds__(256) void kg(
    const float* __restrict__ A, int lda, const int* __restrict__ aidx,
    const float* __restrict__ W, int K, const float* __restrict__ bias,
    const float* __restrict__ other, const float* __restrict__ hprev,
    float* __restrict__ out, int ldo)
{
    gemm_core<P, MODE, ACT>(A, lda, aidx, W, K, bias, other, hprev, out, ldo);
}

// D1: z=0 -> gh0 GEMM + gate0 (reads gi0, writes h0_new)
//     z=1 -> gh1 GEMM (+b_hh1) -> ghbuf
__global__ __launch_bounds__(256) void k_dual(
    const float* __restrict__ h0c, const float* __restrict__ h1c,
    const float* __restrict__ w_hh, const float* __restrict__ b_hh,
    const float* __restrict__ gi0t, float* __restrict__ ghbuf,
    float* __restrict__ h0n)
{
    if (blockIdx.z == 0)
        gemm_core<3, 1, false>(h0c, HID, nullptr, w_hh, HID, b_hh,
                               gi0t, h0c, h0n, HID);
    else
        gemm_core<3, 0, false>(h1c, HID, nullptr, w_hh + (size_t)H3 * HID, HID,
                               b_hh + H3, nullptr, nullptr, ghbuf, H3);
}

// Per-batch attention: scores = H[:,b,:].q1[b], softmax over S, context,
// cc[b] = concat(context, h1[b]). One block per b, 256 threads.
__global__ __launch_bounds__(256) void attn_k(
    const float* __restrict__ H, const float* __restrict__ q1,
    const float* __restrict__ h1, float* __restrict__ cc)
{
    __shared__ float qs[HID];
    __shared__ float sc[SLEN];
    const int b = blockIdx.x, tid = threadIdx.x;

    ((float4*)qs)[tid] = ((const float4*)(q1 + (long)b * HID))[tid];
    __syncthreads();

    const int wave = tid >> 6, lane = tid & 63;
    for (int si = 0; si < 32; ++si) {
        const int s = wave * 32 + si;
        const float* hrow = H + ((long)s * BATCH + b) * HID;
        float p = 0.f;
        #pragma unroll
        for (int i = 0; i < 4; ++i) {
            const int k = i * 256 + lane * 4;
            float4 hv = *(const float4*)(hrow + k);
            float4 qv = *(const float4*)(qs + k);
            p += hv.x * qv.x + hv.y * qv.y + hv.z * qv.z + hv.w * qv.w;
        }
        #pragma unroll
        for (int off = 32; off > 0; off >>= 1) p += __shfl_down(p, off);
        if (lane == 0) sc[s] = p;
    }
    __syncthreads();

    if (tid < 64) {
        float v0 = sc[tid], v1 = sc[tid + 64];
        float m = fmaxf(v0, v1);
        #pragma unroll
        for (int off = 32; off > 0; off >>= 1) m = fmaxf(m, __shfl_xor(m, off));
        float e0 = __expf(v0 - m), e1 = __expf(v1 - m);
        float se = e0 + e1;
        #pragma unroll
        for (int off = 32; off > 0; off >>= 1) se += __shfl_xor(se, off);
        const float inv = 1.f / se;
        sc[tid] = e0 * inv; sc[tid + 64] = e1 * inv;
    }
    __syncthreads();

    float4 acc = make_float4(0.f, 0.f, 0.f, 0.f);
    const float* hb = H + (long)b * HID + tid * 4;
    for (int s = 0; s < SLEN; ++s) {
        const float a = sc[s];
        float4 hv = *(const float4*)(hb + (long)s * BATCH * HID);
        acc.x += a * hv.x; acc.y += a * hv.y;
        acc.z += a * hv.z; acc.w += a * hv.w;
    }
    float* ccb = cc + (long)b * 2 * HID;
    ((float4*)ccb)[tid] = acc;
    ((float4*)(ccb + HID))[tid] = ((const float4*)(h1 + (long)b * HID))[tid];
}

extern "C" void kernel_launch(void* const* d_in, const int* in_sizes, int n_in,
                              void* d_out, int out_size, void* d_ws, size_t ws_size,
                              hipStream_t stream)
{
    const int*   input = (const int*)  d_in[0];
    const float* h_in  = (const float*)d_in[1];
    const float* Hbuf  = (const float*)d_in[2];
    const float* emb   = (const float*)d_in[3];
    const float* w_ih  = (const float*)d_in[4];
    const float* w_hh  = (const float*)d_in[5];
    const float* b_ih  = (const float*)d_in[6];
    const float* b_hh  = (const float*)d_in[7];
    const float* L1    = (const float*)d_in[8];
    const float* L2    = (const float*)d_in[9];

    float* out = (float*)d_out;                         // (T,B,HID)

    // ws layout (floats):
    // [0 .. 4BH)      : h ping-pong: [h0p0][h1p0][h0p1][h1p1]
    // region1 (B*3H)  : ghbuf ; q1buf overlaps (lifetimes disjoint)
    // region2 (B*3H)  : gi0step (fallback) ; ccbuf overlaps
    // gi0all (T*B*3H) : optional hoisted layer-0 input GEMM
    float* ws = (float*)d_ws;
    float* region1 = ws + 4L * BH;
    float* region2 = region1 + (long)BATCH * H3;
    float* gi0all  = region2 + (long)BATCH * H3;
    float* ghbuf   = region1;
    float* q1buf   = region1;
    float* ccbuf   = region2;
    float* gi0step = region2;

    const size_t base_f = (size_t)(gi0all - ws);
    const bool pre = ws_size >= (base_f + (size_t)T_STEPS * BATCH * H3) * sizeof(float);

    // init live h state (ping index 0)
    hipMemcpyAsync(ws, h_in, 2L * BH * sizeof(float),
                   hipMemcpyDeviceToDevice, stream);

    const dim3 blk(256);
    const size_t SM3 = (8192 + 2 * 2 * 3 * 512) * sizeof(unsigned short); // 28672
    const size_t SM1 = (8192 + 2 * 2 * 1 * 512) * sizeof(unsigned short); // 20480

    if (pre) {
        // gi0all = emb[input] @ w_ih0^T + b_ih0 for all T at once
        kg<3, 0, false><<<dim3(64, (T_STEPS * BATCH) / 64), blk, SM3, stream>>>(
            emb, EMBD, input, w_ih, EMBD, b_ih, nullptr, nullptr, gi0all, H3);
    }

    for (int t = 0; t < T_STEPS; ++t) {
        const int cur = t & 1;
        float* hc = ws + (long)cur * 2 * BH;         // h0_prev, h1_prev
        float* hn = ws + (long)(cur ^ 1) * 2 * BH;   // h0_new,  h1_new
        const float* gi0t = pre ? (gi0all + (long)t * BATCH * H3) : gi0step;

        if (!pre)
            kg<3, 0, false><<<dim3(64, 2), blk, SM3, stream>>>(
                emb, EMBD, input + t * BATCH, w_ih, EMBD, b_ih,
                nullptr, nullptr, gi0step, H3);

        // D1: gh0+gate0 (z=0) || gh1 (z=1)
        k_dual<<<dim3(64, 2, 2), blk, SM3, stream>>>(
            hc, hc + BH, w_hh, b_hh, gi0t, ghbuf, hn);
        // D2: gi1 GEMM + gate1
        kg<3, 2, false><<<dim3(64, 2), blk, SM3, stream>>>(
            hn, HID, nullptr, w_ih + (size_t)H3 * EMBD, HID, b_ih + H3,
            ghbuf, hc + BH, hn + BH, HID);
        // D3: q1 = h1_new @ L1^T
        kg<1, 0, false><<<dim3(64, 2), blk, SM1, stream>>>(
            hn + BH, HID, nullptr, L1, HID, nullptr, nullptr, nullptr,
            q1buf, HID);
        // D4: attention + concat
        attn_k<<<dim3(BATCH), blk, 0, stream>>>(Hbuf, q1buf, hn + BH, ccbuf);
        // D5: out = tanh(cc @ L2^T)
        kg<1, 0, true><<<dim3(64, 2), blk, SM1, stream>>>(
            ccbuf, 2 * HID, nullptr, L2, 2 * HID, nullptr, nullptr, nullptr,
            out + (long)t * BH, HID);
    }

    // final state lives in ping index 0 after 64 steps
    hipMemcpyAsync(out + (long)T_STEPS * BH, ws, 2L * BH * sizeof(float),
                   hipMemcpyDeviceToDevice, stream);
}

// Round 3
// 5785.896 us; speedup vs baseline: 3.4557x; 1.8500x over previous
//
#include <hip/hip_runtime.h>

#define T_STEPS 64
#define BATCH   128
#define HID     1024
#define H3      3072
#define EMBD    1024
#define SLEN    128
#define BH      (BATCH * HID)

typedef __attribute__((ext_vector_type(8))) short short8;
typedef __attribute__((ext_vector_type(4))) float f32x4;

__device__ __forceinline__ unsigned short f2bf(float x) {
    unsigned int u = __float_as_uint(x);
    unsigned int r = (u + 0x7fffu + ((u >> 16) & 1u)) >> 16;
    return (unsigned short)r;
}
__device__ __forceinline__ float bf2f(unsigned short h) {
    return __uint_as_float(((unsigned int)h) << 16);
}
__device__ __forceinline__ unsigned int pk(unsigned short a, unsigned short b) {
    return (unsigned int)a | ((unsigned int)b << 16);
}
__device__ __forceinline__ void cvt8(const float4& x, const float4& y,
                                     uint4& H, uint4& L) {
    unsigned short h0 = f2bf(x.x), h1 = f2bf(x.y), h2 = f2bf(x.z), h3 = f2bf(x.w);
    unsigned short h4 = f2bf(y.x), h5 = f2bf(y.y), h6 = f2bf(y.z), h7 = f2bf(y.w);
    unsigned short l0 = f2bf(x.x - bf2f(h0)), l1 = f2bf(x.y - bf2f(h1));
    unsigned short l2 = f2bf(x.z - bf2f(h2)), l3 = f2bf(x.w - bf2f(h3));
    unsigned short l4 = f2bf(y.x - bf2f(h4)), l5 = f2bf(y.y - bf2f(h5));
    unsigned short l6 = f2bf(y.z - bf2f(h6)), l7 = f2bf(y.w - bf2f(h7));
    H = make_uint4(pk(h0,h1), pk(h2,h3), pk(h4,h5), pk(h6,h7));
    L = make_uint4(pk(l0,l1), pk(l2,l3), pk(l4,l5), pk(l6,l7));
}
__device__ __forceinline__ short8 ld8(const unsigned short* p) {
    return *(const short8*)p;
}
__device__ __forceinline__ float sigf(float x) {
    return 1.f / (1.f + __expf(-x));
}

#define TRI(AH, AL, WH, WL, ACC)                                                \
    ACC = __builtin_amdgcn_mfma_f32_16x16x32_bf16(AH, WL, ACC, 0, 0, 0);        \
    ACC = __builtin_amdgcn_mfma_f32_16x16x32_bf16(AL, WH, ACC, 0, 0, 0);        \
    ACC = __builtin_amdgcn_mfma_f32_16x16x32_bf16(AH, WH, ACC, 0, 0, 0);

// ============== plane-conversion kernels (run once per call) ==============
__global__ __launch_bounds__(256) void conv_planes_k(
    const float* __restrict__ src, short* __restrict__ hi, short* __restrict__ lo)
{
    const long i8 = (long)blockIdx.x * 256 + threadIdx.x;
    float4 x = ((const float4*)src)[i8 * 2];
    float4 y = ((const float4*)src)[i8 * 2 + 1];
    uint4 H, L; cvt8(x, y, H, L);
    ((uint4*)hi)[i8] = H; ((uint4*)lo)[i8] = L;
}

// wcat[n][k] = k<1024 ? w_ih1[n][k] : w_hh1[n][k-1024]  (3072 x 2048)
__global__ __launch_bounds__(256) void conv_cat_k(
    const float* __restrict__ wih1, const float* __restrict__ whh1,
    short* __restrict__ hi, short* __restrict__ lo)
{
    const long i8 = (long)blockIdx.x * 256 + threadIdx.x;
    const int k8 = (int)(i8 & 255);
    const long row = i8 >> 8;
    const int k = k8 * 8;
    const float* s = (k < 1024) ? (wih1 + row * 1024 + k) : (whh1 + row * 1024 + (k - 1024));
    float4 x = ((const float4*)s)[0];
    float4 y = ((const float4*)s)[1];
    uint4 H, L; cvt8(x, y, H, L);
    ((uint4*)hi)[i8] = H; ((uint4*)lo)[i8] = L;
}

// gathered embedding rows -> planes (8192 x 1024)
__global__ __launch_bounds__(256) void conv_gather_k(
    const float* __restrict__ emb, const int* __restrict__ input,
    short* __restrict__ hi, short* __restrict__ lo)
{
    const long i8 = (long)blockIdx.x * 256 + threadIdx.x;
    const int c8 = (int)(i8 & 127);
    const long row = i8 >> 7;
    const float* s = emb + (size_t)input[row] * 1024 + c8 * 8;
    float4 x = ((const float4*)s)[0];
    float4 y = ((const float4*)s)[1];
    uint4 H, L; cvt8(x, y, H, L);
    ((uint4*)hi)[i8] = H; ((uint4*)lo)[i8] = L;
}

// ============== pre-split-plane MFMA GEMM ==============
// C = A(M x K) @ W(N x K)^T, A/W given as bf16 hi/lo planes. BK=64 chunks.
// Block 256 thr (4 waves), BM=64 (wave w -> 16-row m-tile), BJ=16 cols/gate.
// MODE 0: outf = acc + bias[p*1024+jc]               (P=3, gi0_all)
// MODE 1: planes store (q1)                          (P=1)
// MODE 2: layer-0 GRU gate: other=gi0_t, bias=b_hh0; writes h f32 + planes
// MODE 3: concat GRU (layer 1): acc{r,z,ni,nh}, bias=b_ih1, bias2=b_hh1
// MODE 4: outf = tanh(acc)                           (P=1, concat A, out)
template<int P, int MODE, bool CONCAT>
__global__ __launch_bounds__(256) void gemm_ps(
    const short* __restrict__ A1h, const short* __restrict__ A1l,
    const short* __restrict__ A2h, const short* __restrict__ A2l,
    const short* __restrict__ Wh,  const short* __restrict__ Wl,
    int K,
    const float* __restrict__ bias, const float* __restrict__ bias2,
    const float* __restrict__ other, const float* __restrict__ hprev,
    float* __restrict__ outf, short* __restrict__ outh, short* __restrict__ outl,
    int ldo)
{
    extern __shared__ short sm[];
    const int ABUF = 8192, WBUF = P * 2048;
    short* Asm = sm;                 // 2 x ABUF  (hi 4096 | lo 4096)
    short* Wsm = sm + 2 * ABUF;      // 2 x WBUF  (hi P*1024 | lo P*1024)
    const int tid = threadIdx.x;
    const int wv = tid >> 6, l = tid & 63;
    const int gl = l >> 4, r16 = l & 15;
    const int bm = blockIdx.x, bj = blockIdx.y;

    const int NC = K >> 6;
    const int NC_half = NC >> 1;

    // ---- A staging: 512 slots (row 0..63 x kgroup 0..7), 2 per thread ----
    const short *a1hP[2], *a1lP[2], *a2hP[2], *a2lP[2];
    int aLds[2];
    const int ldA = CONCAT ? (K >> 1) : K;
    #pragma unroll
    for (int i = 0; i < 2; ++i) {
        const int s = tid + i * 256, row = s >> 3, gg = s & 7;
        const long r = (long)bm * 64 + row;
        a1hP[i] = A1h + r * ldA + gg * 8;
        a1lP[i] = A1l + r * ldA + gg * 8;
        if (CONCAT) {
            a2hP[i] = A2h + r * (K >> 1) + gg * 8;
            a2lP[i] = A2l + r * (K >> 1) + gg * 8;
        } else { a2hP[i] = a1hP[i]; a2lP[i] = a1lP[i]; }
        aLds[i] = ((gg >> 2) * 256 + (row >> 4) * 64 + (gg & 3) * 16 + (row & 15)) * 8;
    }
    // ---- W staging: P*128 slots, threads < P*64 take 2 each ----
    const bool doW = tid < P * 64;
    const short *whP[2], *wlP[2];
    int wLds[2] = {0, 0};
    if (doW) {
        #pragma unroll
        for (int i = 0; i < 2; ++i) {
            const int s = tid + i * P * 64, rowL = s >> 3, gg = s & 7;
            const int p = rowL >> 4, jr = rowL & 15;
            const long grow = (long)(p << 10) + bj * 16 + jr;
            whP[i] = Wh + grow * K + gg * 8;
            wlP[i] = Wl + grow * K + gg * 8;
            wLds[i] = ((gg >> 2) * (P * 64) + p * 64 + (gg & 3) * 16 + jr) * 8;
        }
    }

    constexpr int NACC = (MODE == 3) ? 4 : P;
    f32x4 acc[NACC];
    #pragma unroll
    for (int i = 0; i < NACC; ++i) acc[i] = (f32x4)0.f;

    short8 rAh[2], rAl[2], rWh[2], rWl[2];
    auto LOADC = [&](int c) {
        const bool part1 = !CONCAT || (c < NC_half);
        const long ko = part1 ? (long)c * 64 : (long)c * 64 - (K >> 1);
        #pragma unroll
        for (int i = 0; i < 2; ++i) {
            rAh[i] = *(const short8*)((part1 ? a1hP[i] : a2hP[i]) + ko);
            rAl[i] = *(const short8*)((part1 ? a1lP[i] : a2lP[i]) + ko);
        }
        if (doW) {
            #pragma unroll
            for (int i = 0; i < 2; ++i) {
                rWh[i] = *(const short8*)(whP[i] + (long)c * 64);
                rWl[i] = *(const short8*)(wlP[i] + (long)c * 64);
            }
        }
    };
    auto STORE = [&](int c) {
        const int b = c & 1;
        #pragma unroll
        for (int i = 0; i < 2; ++i) {
            *(short8*)(Asm + b * ABUF + aLds[i]) = rAh[i];
            *(short8*)(Asm + b * ABUF + 4096 + aLds[i]) = rAl[i];
        }
        if (doW) {
            #pragma unroll
            for (int i = 0; i < 2; ++i) {
                *(short8*)(Wsm + b * WBUF + wLds[i]) = rWh[i];
                *(short8*)(Wsm + b * WBUF + P * 1024 + wLds[i]) = rWl[i];
            }
        }
    };

    LOADC(0); STORE(0); LOADC(1);
    __syncthreads();

    for (int c = 0; c < NC; ++c) {
        const int b = c & 1;
        short8 fah[2], fal[2], fwh[2][P], fwl[2][P];
        #pragma unroll
        for (int kc = 0; kc < 2; ++kc) {
            const short* ab = Asm + b * ABUF + (kc * 256 + wv * 64 + l) * 8;
            fah[kc] = *(const short8*)ab;
            fal[kc] = *(const short8*)(ab + 4096);
            #pragma unroll
            for (int p = 0; p < P; ++p) {
                const short* wb = Wsm + b * WBUF + (kc * (P * 64) + p * 64 + l) * 8;
                fwh[kc][p] = *(const short8*)wb;
                fwl[kc][p] = *(const short8*)(wb + P * 1024);
            }
        }
        if (c + 1 < NC) STORE(c + 1);
        if (c + 2 < NC) LOADC(c + 2);
        #pragma unroll
        for (int kc = 0; kc < 2; ++kc) {
            if constexpr (MODE == 3) {
                TRI(fah[kc], fal[kc], fwh[kc][0], fwl[kc][0], acc[0]);
                TRI(fah[kc], fal[kc], fwh[kc][1], fwl[kc][1], acc[1]);
                if (c < NC_half) { TRI(fah[kc], fal[kc], fwh[kc][2], fwl[kc][2], acc[2]); }
                else             { TRI(fah[kc], fal[kc], fwh[kc][2], fwl[kc][2], acc[3]); }
            } else {
                #pragma unroll
                for (int p = 0; p < P; ++p) {
                    TRI(fah[kc], fal[kc], fwh[kc][p], fwl[kc][p], acc[p]);
                }
            }
        }
        __syncthreads();
    }

    const int jc = bj * 16 + r16;
    #pragma unroll
    for (int reg = 0; reg < 4; ++reg) {
        const long R = (long)bm * 64 + wv * 16 + gl * 4 + reg;
        if constexpr (MODE == 0) {
            #pragma unroll
            for (int p = 0; p < P; ++p)
                outf[R * ldo + p * 1024 + jc] = acc[p][reg] + bias[p * 1024 + jc];
        } else if constexpr (MODE == 1) {
            const float v = acc[0][reg];
            const unsigned short hi = f2bf(v), lo = f2bf(v - bf2f(hi));
            outh[R * ldo + jc] = (short)hi; outl[R * ldo + jc] = (short)lo;
        } else if constexpr (MODE == 2) {
            const float* orow = other + R * H3;
            const float rr = sigf(orow[jc] + acc[0][reg] + bias[jc]);
            const float zz = sigf(orow[HID + jc] + acc[1][reg] + bias[HID + jc]);
            const float nn = tanhf(orow[2 * HID + jc] + rr * (acc[2][reg] + bias[2 * HID + jc]));
            const float h = (1.f - zz) * nn + zz * hprev[R * HID + jc];
            outf[R * HID + jc] = h;
            const unsigned short hi = f2bf(h), lo = f2bf(h - bf2f(hi));
            outh[R * HID + jc] = (short)hi; outl[R * HID + jc] = (short)lo;
        } else if constexpr (MODE == 3) {
            const float rr = sigf(acc[0][reg] + bias[jc] + bias2[jc]);
            const float zz = sigf(acc[1][reg] + bias[HID + jc] + bias2[HID + jc]);
            const float nn = tanhf(acc[2][reg] + bias[2 * HID + jc] +
                                   rr * (acc[3][reg] + bias2[2 * HID + jc]));
            const float h = (1.f - zz) * nn + zz * hprev[R * HID + jc];
            outf[R * HID + jc] = h;
            const unsigned short hi = f2bf(h), lo = f2bf(h - bf2f(hi));
            outh[R * HID + jc] = (short)hi; outl[R * HID + jc] = (short)lo;
        } else {
            outf[R * HID + jc] = tanhf(acc[0][reg]);
        }
    }
}

// ============== batched attention scores + softmax (per b) ==============
// scores[t,s] = q1[t,b,:] . H[s,b,:]  (MFMA, bf16 planes), softmax over s,
// writes P_all[t][b][s] f32.  One block per b; M=64(T), N=128(S), K=1024.
__global__ __launch_bounds__(256) void scores_k(
    const short* __restrict__ Qh, const short* __restrict__ Ql,
    const short* __restrict__ Hh, const short* __restrict__ Hl,
    float* __restrict__ Pall)
{
    extern __shared__ short sm[];
    short* Asm = sm;            // 2 x (hi 2048 | lo 2048)
    short* Wsm = sm + 8192;     // 2 x (hi 4096 | lo 4096)
    const int b = blockIdx.x, tid = threadIdx.x;
    const int wv = tid >> 6, l = tid & 63;
    const int gl = l >> 4, cc = l & 15;

    const int ar = tid >> 2, ag = tid & 3;
    const short* qhp = Qh + ((long)ar * BATCH + b) * HID + ag * 8;
    const short* qlp = Ql + ((long)ar * BATCH + b) * HID + ag * 8;
    const int aLds = ((ar >> 4) * 64 + ag * 16 + (ar & 15)) * 8;

    const short *whp[2], *wlp[2]; int wLds[2];
    #pragma unroll
    for (int i = 0; i < 2; ++i) {
        const int s = tid + i * 256, sr = s >> 2, sg = s & 3;
        whp[i] = Hh + ((long)sr * BATCH + b) * HID + sg * 8;
        wlp[i] = Hl + ((long)sr * BATCH + b) * HID + sg * 8;
        wLds[i] = ((sr >> 4) * 64 + sg * 16 + (sr & 15)) * 8;
    }

    f32x4 acc[8];
    #pragma unroll
    for (int i = 0; i < 8; ++i) acc[i] = (f32x4)0.f;

    short8 rAh, rAl, rWh[2], rWl[2];
    auto LOADC = [&](int c) {
        rAh = *(const short8*)(qhp + c * 32);
        rAl = *(const short8*)(qlp + c * 32);
        #pragma unroll
        for (int i = 0; i < 2; ++i) {
            rWh[i] = *(const short8*)(whp[i] + c * 32);
            rWl[i] = *(const short8*)(wlp[i] + c * 32);
        }
    };
    auto STORE = [&](int c) {
        const int bb = c & 1;
        *(short8*)(Asm + bb * 4096 + aLds) = rAh;
        *(short8*)(Asm + bb * 4096 + 2048 + aLds) = rAl;
        #pragma unroll
        for (int i = 0; i < 2; ++i) {
            *(short8*)(Wsm + bb * 8192 + wLds[i]) = rWh[i];
            *(short8*)(Wsm + bb * 8192 + 4096 + wLds[i]) = rWl[i];
        }
    };

    LOADC(0); STORE(0); LOADC(1);
    __syncthreads();
    for (int c = 0; c < 32; ++c) {
        const int bb = c & 1;
        const short* abp = Asm + bb * 4096 + (wv * 64 + l) * 8;
        short8 ah = *(const short8*)abp;
        short8 al = *(const short8*)(abp + 2048);
        if (c + 1 < 32) STORE(c + 1);
        if (c + 2 < 32) LOADC(c + 2);
        #pragma unroll
        for (int jt = 0; jt < 8; ++jt) {
            const short* wbp = Wsm + bb * 8192 + (jt * 64 + l) * 8;
            short8 wh = *(const short8*)wbp;
            short8 wl = *(const short8*)(wbp + 4096);
            TRI(ah, al, wh, wl, acc[jt]);
        }
        __syncthreads();
    }

    #pragma unroll
    for (int reg = 0; reg < 4; ++reg) {
        float m = acc[0][reg];
        #pragma unroll
        for (int jt = 1; jt < 8; ++jt) m = fmaxf(m, acc[jt][reg]);
        #pragma unroll
        for (int off = 1; off < 16; off <<= 1) m = fmaxf(m, __shfl_xor(m, off));
        float e[8], ssum = 0.f;
        #pragma unroll
        for (int jt = 0; jt < 8; ++jt) { e[jt] = __expf(acc[jt][reg] - m); ssum += e[jt]; }
        #pragma unroll
        for (int off = 1; off < 16; off <<= 1) ssum += __shfl_xor(ssum, off);
        const float inv = 1.f / ssum;
        const int t = wv * 16 + gl * 4 + reg;
        #pragma unroll
        for (int jt = 0; jt < 8; ++jt)
            Pall[((long)t * BATCH + b) * SLEN + jt * 16 + cc] = e[jt] * inv;
    }
}

// context[t,b,col] = sum_s P[t,s] * H[s,b,col]; writes ctx planes.
__global__ __launch_bounds__(256) void ctx_k(
    const float* __restrict__ Pall, const float* __restrict__ H,
    short* __restrict__ Ch, short* __restrict__ Cl)
{
    __shared__ float Ps[T_STEPS * SLEN];   // 32 KB
    const int b = blockIdx.x, ht = blockIdx.y, tid = threadIdx.x;
    for (int i = 0; i < 32; ++i) {
        const int idx = i * 256 + tid;
        const int t = idx >> 7, s = idx & 127;
        Ps[idx] = Pall[((long)t * BATCH + b) * SLEN + s];
    }
    __syncthreads();
    const int col = ht * 256 + tid;
    for (int tg = 0; tg < 4; ++tg) {
        float a[16];
        #pragma unroll
        for (int j = 0; j < 16; ++j) a[j] = 0.f;
        for (int s = 0; s < SLEN; ++s) {
            const float hv = H[((long)s * BATCH + b) * HID + col];
            #pragma unroll
            for (int j = 0; j < 16; ++j)
                a[j] = fmaf(Ps[(tg * 16 + j) * SLEN + s], hv, a[j]);
        }
        #pragma unroll
        for (int j = 0; j < 16; ++j) {
            const long row = (long)(tg * 16 + j) * BATCH + b;
            const unsigned short hi = f2bf(a[j]);
            const unsigned short lo = f2bf(a[j] - bf2f(hi));
            Ch[row * HID + col] = (short)hi;
            Cl[row * HID + col] = (short)lo;
        }
    }
}

// ===================== R2 fallback (small-ws) path =====================
template<int P, int MODE, bool ACT>
__device__ __forceinline__ void gemm_core(
    const float* __restrict__ A, int lda, const int* __restrict__ aidx,
    const float* __restrict__ W, int K, const float* __restrict__ bias,
    const float* __restrict__ other, const float* __restrict__ hprev,
    float* __restrict__ out, int ldo)
{
    extern __shared__ __align__(16) unsigned short smem[];
    unsigned short* As = smem;
    unsigned short* Ws = smem + 8192;
    const int tid = threadIdx.x;
    const int w = tid >> 6, l = tid & 63;
    const int g = l >> 4, r16 = l & 15;
    const int bx = blockIdx.x, by = blockIdx.y;

    const int as_row = tid >> 2, as_g = tid & 3;
    const long aR = (long)by * 64 + as_row;
    const float* aptr = (aidx ? A + (size_t)aidx[aR] * lda
                              : A + (size_t)aR * lda) + as_g * 8;
    const int a_slot8 = ((as_row >> 4) * 64 + as_g * 16 + (as_row & 15)) * 8;

    const int WSLOT = P * 64;
    const bool doW = tid >= 256 - WSLOT;
    const float* wptr = nullptr;
    int w_slot8 = 0;
    if (doW) {
        int s = tid - (256 - WSLOT);
        int wrow = s >> 2, wg = s & 3;
        int p = wrow >> 4, jr = wrow & 15;
        int grow = (P == 3 ? p * HID : 0) + bx * 16 + jr;
        wptr = W + (size_t)grow * K + wg * 8;
        w_slot8 = (p * 64 + wg * 16 + jr) * 8;
    }

    f32x4 acc[P];
    #pragma unroll
    for (int p = 0; p < P; ++p) acc[p] = (f32x4)0.f;

    const int NC = K >> 5;
    float4 a0, a1, w0, w1;

    auto LOADC = [&](int c) {
        const float* pa = aptr + c * 32;
        a0 = *(const float4*)pa; a1 = *(const float4*)(pa + 4);
        if (doW) {
            const float* pw = wptr + c * 32;
            w0 = *(const float4*)pw; w1 = *(const float4*)(pw + 4);
        }
    };
    auto CVTW = [&](int c) {
        const int b = c & 1;
        uint4 Hh, Ll;
        cvt8(a0, a1, Hh, Ll);
        *(uint4*)(As + b * 4096 + a_slot8) = Hh;
        *(uint4*)(As + b * 4096 + 2048 + a_slot8) = Ll;
        if (doW) {
            cvt8(w0, w1, Hh, Ll);
            *(uint4*)(Ws + b * (2 * P * 512) + w_slot8) = Hh;
            *(uint4*)(Ws + b * (2 * P * 512) + P * 512 + w_slot8) = Ll;
        }
    };

    LOADC(0); CVTW(0); LOADC(1);
    __syncthreads();

    for (int c = 0; c < NC; ++c) {
        const int b = c & 1;
        const unsigned short* aB = As + b * 4096 + (w * 64 + l) * 8;
        short8 ah = ld8(aB);
        short8 al = ld8(aB + 2048);
        short8 wh[P], wl[P];
        #pragma unroll
        for (int p = 0; p < P; ++p) {
            const unsigned short* wB = Ws + b * (2 * P * 512) + (p * 64 + l) * 8;
            wh[p] = ld8(wB);
            wl[p] = ld8(wB + P * 512);
        }
        if (c + 1 < NC) CVTW(c + 1);
        if (c + 2 < NC) LOADC(c + 2);
        #pragma unroll
        for (int p = 0; p < P; ++p) {
            acc[p] = __builtin_amdgcn_mfma_f32_16x16x32_bf16(ah, wl[p], acc[p], 0, 0, 0);
            acc[p] = __builtin_amdgcn_mfma_f32_16x16x32_bf16(al, wh[p], acc[p], 0, 0, 0);
            acc[p] = __builtin_amdgcn_mfma_f32_16x16x32_bf16(ah, wh[p], acc[p], 0, 0, 0);
        }
        __syncthreads();
    }

    const int jc = bx * 16 + r16;
    if (MODE == 0) {
        #pragma unroll
        for (int p = 0; p < P; ++p) {
            const int colbase = (P == 3 ? p * HID : 0);
            const float bv = bias ? bias[colbase + jc] : 0.f;
            #pragma unroll
            for (int reg = 0; reg < 4; ++reg) {
                const long R = (long)by * 64 + w * 16 + g * 4 + reg;
                float v = acc[p][reg] + bv;
                if (ACT) v = tanhf(v);
                out[R * (long)ldo + colbase + jc] = v;
            }
        }
    } else {
        const float br = bias[jc], bz = bias[HID + jc], bn = bias[2 * HID + jc];
        #pragma unroll
        for (int reg = 0; reg < 4; ++reg) {
            const long R = (long)by * 64 + w * 16 + g * 4 + reg;
            const float Gr = acc[0][reg] + br;
            const float Gz = acc[1][reg] + bz;
            const float Gn = acc[2][reg] + bn;
            const float* orow = other + R * (long)H3;
            const float o_r = orow[jc], o_z = orow[HID + jc], o_n = orow[2 * HID + jc];
            const float hp = hprev[R * (long)HID + jc];
            float rr, zz, nn;
            if (MODE == 1) {
                rr = sigf(o_r + Gr); zz = sigf(o_z + Gz);
                nn = tanhf(o_n + rr * Gn);
            } else {
                rr = sigf(Gr + o_r); zz = sigf(Gz + o_z);
                nn = tanhf(Gn + rr * o_n);
            }
            out[R * (long)HID + jc] = (1.f - zz) * nn + zz * hp;
        }
    }
}

template<int P, int MODE, bool ACT>
__global__ __launch_bounds__(256) void kg(
    const float* __restrict__ A, int lda, const int* __restrict__ aidx,
    const float* __restrict__ W, int K, const float* __restrict__ bias,
    const float* __restrict__ other, const float* __restrict__ hprev,
    float* __restrict__ out, int ldo)
{
    gemm_core<P, MODE, ACT>(A, lda, aidx, W, K, bias, other, hprev, out, ldo);
}

__global__ __launch_bounds__(256) void k_dual(
    const float* __restrict__ h0c, const float* __restrict__ h1c,
    const float* __restrict__ w_hh, const float* __restrict__ b_hh,
    const float* __restrict__ gi0t, float* __restrict__ ghbuf,
    float* __restrict__ h0n)
{
    if (blockIdx.z == 0)
        gemm_core<3, 1, false>(h0c, HID, nullptr, w_hh, HID, b_hh,
                               gi0t, h0c, h0n, HID);
    else
        gemm_core<3, 0, false>(h1c, HID, nullptr, w_hh + (size_t)H3 * HID, HID,
                               b_hh + H3, nullptr, nullptr, ghbuf, H3);
}

__global__ __launch_bounds__(256) void attn_k(
    const float* __restrict__ H, const float* __restrict__ q1,
    const float* __restrict__ h1, float* __restrict__ cc)
{
    __shared__ float qs[HID];
    __shared__ float sc[SLEN];
    const int b = blockIdx.x, tid = threadIdx.x;

    ((float4*)qs)[tid] = ((const float4*)(q1 + (long)b * HID))[tid];
    __syncthreads();

    const int wave = tid >> 6, lane = tid & 63;
    for (int si = 0; si < 32; ++si) {
        const int s = wave * 32 + si;
        const float* hrow = H + ((long)s * BATCH + b) * HID;
        float p = 0.f;
        #pragma unroll
        for (int i = 0; i < 4; ++i) {
            const int k = i * 256 + lane * 4;
            float4 hv = *(const float4*)(hrow + k);
            float4 qv = *(const float4*)(qs + k);
            p += hv.x * qv.x + hv.y * qv.y + hv.z * qv.z + hv.w * qv.w;
        }
        #pragma unroll
        for (int off = 32; off > 0; off >>= 1) p += __shfl_down(p, off);
        if (lane == 0) sc[s] = p;
    }
    __syncthreads();

    if (tid < 64) {
        float v0 = sc[tid], v1 = sc[tid + 64];
        float m = fmaxf(v0, v1);
        #pragma unroll
        for (int off = 32; off > 0; off >>= 1) m = fmaxf(m, __shfl_xor(m, off));
        float e0 = __expf(v0 - m), e1 = __expf(v1 - m);
        float se = e0 + e1;
        #pragma unroll
        for (int off = 32; off > 0; off >>= 1) se += __shfl_xor(se, off);
        const float inv = 1.f / se;
        sc[tid] = e0 * inv; sc[tid + 64] = e1 * inv;
    }
    __syncthreads();

    float4 acc = make_float4(0.f, 0.f, 0.f, 0.f);
    const float* hb = H + (long)b * HID + tid * 4;
    for (int s = 0; s < SLEN; ++s) {
        const float a = sc[s];
        float4 hv = *(const float4*)(hb + (long)s * BATCH * HID);
        acc.x += a * hv.x; acc.y += a * hv.y;
        acc.z += a * hv.z; acc.w += a * hv.w;
    }
    float* ccb = cc + (long)b * 2 * HID;
    ((float4*)ccb)[tid] = acc;
    ((float4*)(ccb + HID))[tid] = ((const float4*)(h1 + (long)b * HID))[tid];
}

// =========================== launch ===========================
extern "C" void kernel_launch(void* const* d_in, const int* in_sizes, int n_in,
                              void* d_out, int out_size, void* d_ws, size_t ws_size,
                              hipStream_t stream)
{
    const int*   input = (const int*)  d_in[0];
    const float* h_in  = (const float*)d_in[1];
    const float* Hbuf  = (const float*)d_in[2];
    const float* emb   = (const float*)d_in[3];
    const float* w_ih  = (const float*)d_in[4];
    const float* w_hh  = (const float*)d_in[5];
    const float* b_ih  = (const float*)d_in[6];
    const float* b_hh  = (const float*)d_in[7];
    const float* L1    = (const float*)d_in[8];
    const float* L2    = (const float*)d_in[9];

    float* out = (float*)d_out;                         // (T,B,HID) + (2,B,HID)

    // ---- fast-path ws plan (bump allocator) ----
    char* basep = (char*)d_ws;
    size_t off = 0;
    auto alloc = [&](size_t bytes) -> char* {
        off = (off + 255) & ~(size_t)255;
        char* p = basep + off; off += bytes; return p;
    };
    short* wih0h = (short*)alloc(3072L*1024*2); short* wih0l = (short*)alloc(3072L*1024*2);
    short* whh0h = (short*)alloc(3072L*1024*2); short* whh0l = (short*)alloc(3072L*1024*2);
    short* wcath = (short*)alloc(3072L*2048*2); short* wcatl = (short*)alloc(3072L*2048*2);
    short* l1h   = (short*)alloc(1024L*1024*2); short* l1l   = (short*)alloc(1024L*1024*2);
    short* l2h   = (short*)alloc(1024L*2048*2); short* l2l   = (short*)alloc(1024L*2048*2);
    short* Hh    = (short*)alloc(16777216L*2);  short* Hl    = (short*)alloc(16777216L*2);
    short* hih   = (short*)alloc(262144L*2);    short* hil   = (short*)alloc(262144L*2);
    short* h0ah  = (short*)alloc(8388608L*2);   short* h0al  = (short*)alloc(8388608L*2);
    short* h1ah  = (short*)alloc(8388608L*2);   short* h1al  = (short*)alloc(8388608L*2);
    short* eqh   = (short*)alloc(8388608L*2);   short* eql   = (short*)alloc(8388608L*2);
    float* gi0   = (float*)alloc(25165824L*4);
    float* h0f   = (float*)alloc(262144L*4);
    float* h1f   = (float*)alloc(8388608L*4);
    float* Pall  = (float*)alloc(1048576L*4);
    short* ctxh  = (short*)gi0;                 // gi0 dead after loop A
    short* ctxl  = ctxh + 8388608L;

    const dim3 blk(256);
    const size_t SM3 = (2 * 8192 + 2 * 3 * 2048) * sizeof(short);  // 57344
    const size_t SM1 = (2 * 8192 + 2 * 1 * 2048) * sizeof(short);  // 40960

    if (off <= ws_size) {
        // ---- phase 0: plane conversions ----
        conv_planes_k<<<1536, blk, 0, stream>>>(w_ih, wih0h, wih0l);
        conv_planes_k<<<1536, blk, 0, stream>>>(w_hh, whh0h, whh0l);
        conv_cat_k<<<3072, blk, 0, stream>>>(w_ih + (size_t)H3 * EMBD,
                                             w_hh + (size_t)H3 * HID, wcath, wcatl);
        conv_planes_k<<<512,  blk, 0, stream>>>(L1, l1h, l1l);
        conv_planes_k<<<1024, blk, 0, stream>>>(L2, l2h, l2l);
        conv_planes_k<<<8192, blk, 0, stream>>>(Hbuf, Hh, Hl);
        conv_planes_k<<<128,  blk, 0, stream>>>(h_in, hih, hil);
        conv_gather_k<<<4096, blk, 0, stream>>>(emb, input, eqh, eql);

        // gi0_all = E @ w_ih0^T + b_ih0   (8192 x 3072)
        gemm_ps<3, 0, false><<<dim3(128, 64), blk, SM3, stream>>>(
            eqh, eql, nullptr, nullptr, wih0h, wih0l, 1024,
            b_ih, nullptr, nullptr, nullptr, gi0, nullptr, nullptr, H3);

        // ---- phase 1: h0 recurrence ----
        for (int t = 0; t < T_STEPS; ++t) {
            const short* a1h = t ? h0ah + (long)(t - 1) * BH : hih;
            const short* a1l = t ? h0al + (long)(t - 1) * BH : hil;
            const float* hp  = t ? h0f + (long)((t - 1) & 1) * BH : h_in;
            gemm_ps<3, 2, false><<<dim3(2, 64), blk, SM3, stream>>>(
                a1h, a1l, nullptr, nullptr, whh0h, whh0l, 1024,
                b_hh, nullptr, gi0 + (long)t * BATCH * H3, hp,
                h0f + (long)(t & 1) * BH, h0ah + (long)t * BH, h0al + (long)t * BH, HID);
        }
        // ---- phase 2: h1 recurrence (concat GEMM K=2048) ----
        for (int t = 0; t < T_STEPS; ++t) {
            const short* a2h = t ? h1ah + (long)(t - 1) * BH : hih + BH;
            const short* a2l = t ? h1al + (long)(t - 1) * BH : hil + BH;
            const float* hp  = t ? h1f + (long)(t - 1) * BH : h_in + BH;
            gemm_ps<3, 3, true><<<dim3(2, 64), blk, SM3, stream>>>(
                h0ah + (long)t * BH, h0al + (long)t * BH, a2h, a2l,
                wcath, wcatl, 2048,
                b_ih + H3, b_hh + H3, nullptr, hp,
                h1f + (long)t * BH, h1ah + (long)t * BH, h1al + (long)t * BH, HID);
        }
        // ---- phase 3: batched attention + output ----
        gemm_ps<1, 1, false><<<dim3(128, 64), blk, SM1, stream>>>(
            h1ah, h1al, nullptr, nullptr, l1h, l1l, 1024,
            nullptr, nullptr, nullptr, nullptr, nullptr, eqh, eql, HID);
        scores_k<<<dim3(BATCH), blk, 49152, stream>>>(eqh, eql, Hh, Hl, Pall);
        ctx_k<<<dim3(BATCH, 4), blk, 0, stream>>>(Pall, Hbuf, ctxh, ctxl);
        gemm_ps<1, 4, true><<<dim3(128, 64), blk, SM1, stream>>>(
            ctxh, ctxl, h1ah, h1al, l2h, l2l, 2048,
            nullptr, nullptr, nullptr, nullptr, out, nullptr, nullptr, HID);

        hipMemcpyAsync(out + (long)T_STEPS * BH, h0f + BH, (size_t)BH * 4,
                       hipMemcpyDeviceToDevice, stream);
        hipMemcpyAsync(out + (long)T_STEPS * BH + BH, h1f + 63L * BH, (size_t)BH * 4,
                       hipMemcpyDeviceToDevice, stream);
        return;
    }

    // =================== fallback: R2 path ===================
    float* hst = out + (long)T_STEPS * BATCH * HID;
    float* ws  = (float*)d_ws;
    float* region1 = ws + 4L * BH;
    float* region2 = region1 + (long)BATCH * H3;
    float* gi0all  = region2 + (long)BATCH * H3;
    float* ghbuf   = region1;
    float* q1buf   = region1;
    float* ccbuf   = region2;
    float* gi0step = region2;

    const size_t base_f = (size_t)(gi0all - ws);
    const bool pre = ws_size >= (base_f + (size_t)T_STEPS * BATCH * H3) * sizeof(float);

    hipMemcpyAsync(ws, h_in, 2L * BH * sizeof(float), hipMemcpyDeviceToDevice, stream);

    const size_t FSM3 = (8192 + 2 * 2 * 3 * 512) * sizeof(unsigned short);
    const size_t FSM1 = (8192 + 2 * 2 * 1 * 512) * sizeof(unsigned short);

    if (pre) {
        kg<3, 0, false><<<dim3(64, (T_STEPS * BATCH) / 64), blk, FSM3, stream>>>(
            emb, EMBD, input, w_ih, EMBD, b_ih, nullptr, nullptr, gi0all, H3);
    }
    for (int t = 0; t < T_STEPS; ++t) {
        const int cur = t & 1;
        float* hc = ws + (long)cur * 2 * BH;
        float* hn = ws + (long)(cur ^ 1) * 2 * BH;
        const float* gi0t = pre ? (gi0all + (long)t * BATCH * H3) : gi0step;
        if (!pre)
            kg<3, 0, false><<<dim3(64, 2), blk, FSM3, stream>>>(
                emb, EMBD, input + t * BATCH, w_ih, EMBD, b_ih,
                nullptr, nullptr, gi0step, H3);
        k_dual<<<dim3(64, 2, 2), blk, FSM3, stream>>>(
            hc, hc + BH, w_hh, b_hh, gi0t, ghbuf, hn);
        kg<3, 2, false><<<dim3(64, 2), blk, FSM3, stream>>>(
            hn, HID, nullptr, w_ih + (size_t)H3 * EMBD, HID, b_ih + H3,
            ghbuf, hc + BH, hn + BH, HID);
        kg<1, 0, false><<<dim3(64, 2), blk, FSM1, stream>>>(
            hn + BH, HID, nullptr, L1, HID, nullptr, nullptr, nullptr,
            q1buf, HID);
        attn_k<<<dim3(BATCH), blk, 0, stream>>>(Hbuf, q1buf, hn + BH, ccbuf);
        kg<1, 0, true><<<dim3(64, 2), blk, FSM1, stream>>>(
            ccbuf, 2 * HID, nullptr, L2, 2 * HID, nullptr, nullptr, nullptr,
            out + (long)t * BH, HID);
    }
    hipMemcpyAsync(out + (long)T_STEPS * BH, ws, 2L * BH * sizeof(float),
                   hipMemcpyDeviceToDevice, stream);
}

// Round 4
// 4093.601 us; speedup vs baseline: 4.8842x; 1.4134x over previous
//
#include <hip/hip_runtime.h>

#define T_STEPS 64
#define BATCH   128
#define HID     1024
#define H3      3072
#define EMBD    1024
#define SLEN    128
#define BH      (BATCH * HID)

typedef __attribute__((ext_vector_type(8))) short short8;
typedef __attribute__((ext_vector_type(4))) float f32x4;

__device__ __forceinline__ unsigned short f2bf(float x) {
    unsigned int u = __float_as_uint(x);
    unsigned int r = (u + 0x7fffu + ((u >> 16) & 1u)) >> 16;
    return (unsigned short)r;
}
__device__ __forceinline__ float bf2f(unsigned short h) {
    return __uint_as_float(((unsigned int)h) << 16);
}
__device__ __forceinline__ unsigned int pk(unsigned short a, unsigned short b) {
    return (unsigned int)a | ((unsigned int)b << 16);
}
__device__ __forceinline__ void cvt8(const float4& x, const float4& y,
                                     uint4& H, uint4& L) {
    unsigned short h0 = f2bf(x.x), h1 = f2bf(x.y), h2 = f2bf(x.z), h3 = f2bf(x.w);
    unsigned short h4 = f2bf(y.x), h5 = f2bf(y.y), h6 = f2bf(y.z), h7 = f2bf(y.w);
    unsigned short l0 = f2bf(x.x - bf2f(h0)), l1 = f2bf(x.y - bf2f(h1));
    unsigned short l2 = f2bf(x.z - bf2f(h2)), l3 = f2bf(x.w - bf2f(h3));
    unsigned short l4 = f2bf(y.x - bf2f(h4)), l5 = f2bf(y.y - bf2f(h5));
    unsigned short l6 = f2bf(y.z - bf2f(h6)), l7 = f2bf(y.w - bf2f(h7));
    H = make_uint4(pk(h0,h1), pk(h2,h3), pk(h4,h5), pk(h6,h7));
    L = make_uint4(pk(l0,l1), pk(l2,l3), pk(l4,l5), pk(l6,l7));
}
__device__ __forceinline__ float sigf(float x) {
    return 1.f / (1.f + __expf(-x));
}

#define TRI(AH, AL, WH, WL, ACC)                                                \
    ACC = __builtin_amdgcn_mfma_f32_16x16x32_bf16(AH, WL, ACC, 0, 0, 0);        \
    ACC = __builtin_amdgcn_mfma_f32_16x16x32_bf16(AL, WH, ACC, 0, 0, 0);        \
    ACC = __builtin_amdgcn_mfma_f32_16x16x32_bf16(AH, WH, ACC, 0, 0, 0);

// ============== plane-conversion kernels (run once per call) ==============
__global__ __launch_bounds__(256) void conv_planes_k(
    const float* __restrict__ src, short* __restrict__ hi, short* __restrict__ lo)
{
    const long i8 = (long)blockIdx.x * 256 + threadIdx.x;
    float4 x = ((const float4*)src)[i8 * 2];
    float4 y = ((const float4*)src)[i8 * 2 + 1];
    uint4 H, L; cvt8(x, y, H, L);
    ((uint4*)hi)[i8] = H; ((uint4*)lo)[i8] = L;
}

// gathered embedding rows -> planes (8192 x 1024)
__global__ __launch_bounds__(256) void conv_gather_k(
    const float* __restrict__ emb, const int* __restrict__ input,
    short* __restrict__ hi, short* __restrict__ lo)
{
    const long i8 = (long)blockIdx.x * 256 + threadIdx.x;
    const int c8 = (int)(i8 & 127);
    const long row = i8 >> 7;
    const float* s = emb + (size_t)input[row] * 1024 + c8 * 8;
    float4 x = ((const float4*)s)[0];
    float4 y = ((const float4*)s)[1];
    uint4 H, L; cvt8(x, y, H, L);
    ((uint4*)hi)[i8] = H; ((uint4*)lo)[i8] = L;
}

// ============== pre-split-plane MFMA GEMM ==============
// C = A(M x K) @ W(N x K)^T, A/W given as bf16 hi/lo planes. BK=64 chunks.
// Block 256 thr (4 waves), BM=64 (wave w -> 16-row m-tile), BJ=16 cols/gate.
// LDS staging is LINEAR in thread id (conflict-free ds_write_b128); the
// GLOBAL address is derived from the slot -> (row, kgroup) map (m173 pattern).
// MODE 0: outf = acc + bias[p*1024+jc]               (P=3, gi batches)
// MODE 1: planes store (q1)                          (P=1)
// MODE 2: GRU gate: other=gi_t, bias=b_hh; writes h f32 + planes
// MODE 4: outf = tanh(acc)                           (P=1, concat A, out)
template<int P, int MODE, bool CONCAT>
__global__ __launch_bounds__(256) void gemm_ps(
    const short* __restrict__ A1h, const short* __restrict__ A1l,
    const short* __restrict__ A2h, const short* __restrict__ A2l,
    const short* __restrict__ Wh,  const short* __restrict__ Wl,
    int K,
    const float* __restrict__ bias, const float* __restrict__ bias2,
    const float* __restrict__ other, const float* __restrict__ hprev,
    float* __restrict__ outf, short* __restrict__ outh, short* __restrict__ outl,
    int ldo)
{
    extern __shared__ short sm[];
    const int ABUF = 8192, WBUF = P * 2048;
    short* Asm = sm;                 // 2 x ABUF  (hi 4096 | lo 4096)
    short* Wsm = sm + 2 * ABUF;      // 2 x WBUF  (hi P*1024 | lo P*1024)
    const int tid = threadIdx.x;
    const int wv = tid >> 6, l = tid & 63;
    const int gl = l >> 4, r16 = l & 15;
    const int bm = blockIdx.x, bj = blockIdx.y;

    const int NC = K >> 6;
    const int NC_half = NC >> 1;

    // ---- A staging: 512 linear slots; slot s -> row,kg ----
    const short *a1hP[2], *a1lP[2], *a2hP[2], *a2lP[2];
    int aLds[2];
    const int ldA = CONCAT ? (K >> 1) : K;
    #pragma unroll
    for (int i = 0; i < 2; ++i) {
        const int s = tid + i * 256;
        const int row = ((s >> 6) & 3) * 16 + (s & 15);
        const int kg  = ((s >> 8) << 2) | ((s >> 4) & 3);
        const long r = (long)bm * 64 + row;
        a1hP[i] = A1h + r * ldA + kg * 8;
        a1lP[i] = A1l + r * ldA + kg * 8;
        if (CONCAT) {
            a2hP[i] = A2h + r * (K >> 1) + kg * 8;
            a2lP[i] = A2l + r * (K >> 1) + kg * 8;
        } else { a2hP[i] = a1hP[i]; a2lP[i] = a1lP[i]; }
        aLds[i] = s * 8;
    }
    // ---- W staging: P*128 linear slots, threads < P*64 take 2 each ----
    const bool doW = tid < P * 64;
    const short *whP[2], *wlP[2];
    int wLds[2] = {0, 0};
    if (doW) {
        #pragma unroll
        for (int i = 0; i < 2; ++i) {
            const int s = tid + i * P * 64;
            const int kcw = s / (P * 64);
            const int rem = s - kcw * (P * 64);
            const int p = rem >> 6, ll = rem & 63;
            const int jr = ll & 15, g = ll >> 4;
            const int kg = kcw * 4 + g;
            const long grow = (long)(p << 10) + bj * 16 + jr;
            whP[i] = Wh + grow * K + kg * 8;
            wlP[i] = Wl + grow * K + kg * 8;
            wLds[i] = s * 8;
        }
    }

    f32x4 acc[P];
    #pragma unroll
    for (int i = 0; i < P; ++i) acc[i] = (f32x4)0.f;

    short8 rAh[2], rAl[2], rWh[2], rWl[2];
    auto LOADC = [&](int c) {
        const bool part1 = !CONCAT || (c < NC_half);
        const long ko = part1 ? (long)c * 64 : (long)c * 64 - (K >> 1);
        #pragma unroll
        for (int i = 0; i < 2; ++i) {
            rAh[i] = *(const short8*)((part1 ? a1hP[i] : a2hP[i]) + ko);
            rAl[i] = *(const short8*)((part1 ? a1lP[i] : a2lP[i]) + ko);
        }
        if (doW) {
            #pragma unroll
            for (int i = 0; i < 2; ++i) {
                rWh[i] = *(const short8*)(whP[i] + (long)c * 64);
                rWl[i] = *(const short8*)(wlP[i] + (long)c * 64);
            }
        }
    };
    auto STORE = [&](int c) {
        const int b = c & 1;
        #pragma unroll
        for (int i = 0; i < 2; ++i) {
            *(short8*)(Asm + b * ABUF + aLds[i]) = rAh[i];
            *(short8*)(Asm + b * ABUF + 4096 + aLds[i]) = rAl[i];
        }
        if (doW) {
            #pragma unroll
            for (int i = 0; i < 2; ++i) {
                *(short8*)(Wsm + b * WBUF + wLds[i]) = rWh[i];
                *(short8*)(Wsm + b * WBUF + P * 1024 + wLds[i]) = rWl[i];
            }
        }
    };

    LOADC(0); STORE(0); LOADC(1);
    __syncthreads();

    for (int c = 0; c < NC; ++c) {
        const int b = c & 1;
        short8 fah[2], fal[2], fwh[2][P], fwl[2][P];
        #pragma unroll
        for (int kc = 0; kc < 2; ++kc) {
            const short* ab = Asm + b * ABUF + (kc * 256 + wv * 64 + l) * 8;
            fah[kc] = *(const short8*)ab;
            fal[kc] = *(const short8*)(ab + 4096);
            #pragma unroll
            for (int p = 0; p < P; ++p) {
                const short* wb = Wsm + b * WBUF + (kc * (P * 64) + p * 64 + l) * 8;
                fwh[kc][p] = *(const short8*)wb;
                fwl[kc][p] = *(const short8*)(wb + P * 1024);
            }
        }
        if (c + 1 < NC) STORE(c + 1);
        if (c + 2 < NC) LOADC(c + 2);
        #pragma unroll
        for (int kc = 0; kc < 2; ++kc) {
            #pragma unroll
            for (int p = 0; p < P; ++p) {
                TRI(fah[kc], fal[kc], fwh[kc][p], fwl[kc][p], acc[p]);
            }
        }
        __syncthreads();
    }

    const int jc = bj * 16 + r16;
    #pragma unroll
    for (int reg = 0; reg < 4; ++reg) {
        const long R = (long)bm * 64 + wv * 16 + gl * 4 + reg;
        if constexpr (MODE == 0) {
            #pragma unroll
            for (int p = 0; p < P; ++p)
                outf[R * ldo + p * 1024 + jc] = acc[p][reg] + bias[p * 1024 + jc];
        } else if constexpr (MODE == 1) {
            const float v = acc[0][reg];
            const unsigned short hi = f2bf(v), lo = f2bf(v - bf2f(hi));
            outh[R * ldo + jc] = (short)hi; outl[R * ldo + jc] = (short)lo;
        } else if constexpr (MODE == 2) {
            const float* orow = other + R * H3;
            const float rr = sigf(orow[jc] + acc[0][reg] + bias[jc]);
            const float zz = sigf(orow[HID + jc] + acc[1][reg] + bias[HID + jc]);
            const float nn = tanhf(orow[2 * HID + jc] + rr * (acc[2][reg] + bias[2 * HID + jc]));
            const float h = (1.f - zz) * nn + zz * hprev[R * HID + jc];
            outf[R * HID + jc] = h;
            const unsigned short hi = f2bf(h), lo = f2bf(h - bf2f(hi));
            outh[R * HID + jc] = (short)hi; outl[R * HID + jc] = (short)lo;
        } else {
            outf[R * HID + jc] = tanhf(acc[0][reg]);
        }
    }
}

// ============== batched attention scores + softmax (per b) ==============
// scores[t,s] = q1[t,b,:] . H[s,b,:]  (MFMA, bf16 planes), softmax over s,
// writes P_all[t][b][s] f32.  One block per b; M=64(T), N=128(S), K=1024.
__global__ __launch_bounds__(256) void scores_k(
    const short* __restrict__ Qh, const short* __restrict__ Ql,
    const short* __restrict__ Hh, const short* __restrict__ Hl,
    float* __restrict__ Pall)
{
    extern __shared__ short sm[];
    short* Asm = sm;            // 2 x (hi 2048 | lo 2048)
    short* Wsm = sm + 8192;     // 2 x (hi 4096 | lo 4096)
    const int b = blockIdx.x, tid = threadIdx.x;
    const int wv = tid >> 6, l = tid & 63;
    const int gl = l >> 4, cc = l & 15;

    // A (Q): 256 linear slots; s -> row,g
    const int arow = ((tid >> 6) & 3) * 16 + (tid & 15);
    const int ag   = (tid >> 4) & 3;
    const short* qhp = Qh + ((long)arow * BATCH + b) * HID + ag * 8;
    const short* qlp = Ql + ((long)arow * BATCH + b) * HID + ag * 8;
    const int aLds = tid * 8;

    // W (H): 512 linear slots, 2 per thread; s -> srow,g
    const short *whp[2], *wlp[2]; int wLds[2];
    #pragma unroll
    for (int i = 0; i < 2; ++i) {
        const int s = tid + i * 256;
        const int srow = ((s >> 6) & 7) * 16 + (s & 15);
        const int sg   = (s >> 4) & 3;
        whp[i] = Hh + ((long)srow * BATCH + b) * HID + sg * 8;
        wlp[i] = Hl + ((long)srow * BATCH + b) * HID + sg * 8;
        wLds[i] = s * 8;
    }

    f32x4 acc[8];
    #pragma unroll
    for (int i = 0; i < 8; ++i) acc[i] = (f32x4)0.f;

    short8 rAh, rAl, rWh[2], rWl[2];
    auto LOADC = [&](int c) {
        rAh = *(const short8*)(qhp + c * 32);
        rAl = *(const short8*)(qlp + c * 32);
        #pragma unroll
        for (int i = 0; i < 2; ++i) {
            rWh[i] = *(const short8*)(whp[i] + c * 32);
            rWl[i] = *(const short8*)(wlp[i] + c * 32);
        }
    };
    auto STORE = [&](int c) {
        const int bb = c & 1;
        *(short8*)(Asm + bb * 4096 + aLds) = rAh;
        *(short8*)(Asm + bb * 4096 + 2048 + aLds) = rAl;
        #pragma unroll
        for (int i = 0; i < 2; ++i) {
            *(short8*)(Wsm + bb * 8192 + wLds[i]) = rWh[i];
            *(short8*)(Wsm + bb * 8192 + 4096 + wLds[i]) = rWl[i];
        }
    };

    LOADC(0); STORE(0); LOADC(1);
    __syncthreads();
    for (int c = 0; c < 32; ++c) {
        const int bb = c & 1;
        const short* abp = Asm + bb * 4096 + (wv * 64 + l) * 8;
        short8 ah = *(const short8*)abp;
        short8 al = *(const short8*)(abp + 2048);
        if (c + 1 < 32) STORE(c + 1);
        if (c + 2 < 32) LOADC(c + 2);
        #pragma unroll
        for (int jt = 0; jt < 8; ++jt) {
            const short* wbp = Wsm + bb * 8192 + (jt * 64 + l) * 8;
            short8 wh = *(const short8*)wbp;
            short8 wl = *(const short8*)(wbp + 4096);
            TRI(ah, al, wh, wl, acc[jt]);
        }
        __syncthreads();
    }

    #pragma unroll
    for (int reg = 0; reg < 4; ++reg) {
        float m = acc[0][reg];
        #pragma unroll
        for (int jt = 1; jt < 8; ++jt) m = fmaxf(m, acc[jt][reg]);
        #pragma unroll
        for (int off = 1; off < 16; off <<= 1) m = fmaxf(m, __shfl_xor(m, off));
        float e[8], ssum = 0.f;
        #pragma unroll
        for (int jt = 0; jt < 8; ++jt) { e[jt] = __expf(acc[jt][reg] - m); ssum += e[jt]; }
        #pragma unroll
        for (int off = 1; off < 16; off <<= 1) ssum += __shfl_xor(ssum, off);
        const float inv = 1.f / ssum;
        const int t = wv * 16 + gl * 4 + reg;
        #pragma unroll
        for (int jt = 0; jt < 8; ++jt)
            Pall[((long)t * BATCH + b) * SLEN + jt * 16 + cc] = e[jt] * inv;
    }
}

// context[t,b,col] = sum_s P[t,s] * H[s,b,col]; writes ctx planes.
__global__ __launch_bounds__(256) void ctx_k(
    const float* __restrict__ Pall, const float* __restrict__ H,
    short* __restrict__ Ch, short* __restrict__ Cl)
{
    __shared__ float Ps[T_STEPS * SLEN];   // 32 KB
    const int b = blockIdx.x, ht = blockIdx.y, tid = threadIdx.x;
    for (int i = 0; i < 32; ++i) {
        const int idx = i * 256 + tid;
        const int t = idx >> 7, s = idx & 127;
        Ps[idx] = Pall[((long)t * BATCH + b) * SLEN + s];
    }
    __syncthreads();
    const int col = ht * 256 + tid;
    for (int tg = 0; tg < 4; ++tg) {
        float a[16];
        #pragma unroll
        for (int j = 0; j < 16; ++j) a[j] = 0.f;
        for (int s = 0; s < SLEN; ++s) {
            const float hv = H[((long)s * BATCH + b) * HID + col];
            #pragma unroll
            for (int j = 0; j < 16; ++j)
                a[j] = fmaf(Ps[(tg * 16 + j) * SLEN + s], hv, a[j]);
        }
        #pragma unroll
        for (int j = 0; j < 16; ++j) {
            const long row = (long)(tg * 16 + j) * BATCH + b;
            const unsigned short hi = f2bf(a[j]);
            const unsigned short lo = f2bf(a[j] - bf2f(hi));
            Ch[row * HID + col] = (short)hi;
            Cl[row * HID + col] = (short)lo;
        }
    }
}

// =========================== launch ===========================
extern "C" void kernel_launch(void* const* d_in, const int* in_sizes, int n_in,
                              void* d_out, int out_size, void* d_ws, size_t ws_size,
                              hipStream_t stream)
{
    const int*   input = (const int*)  d_in[0];
    const float* h_in  = (const float*)d_in[1];
    const float* Hbuf  = (const float*)d_in[2];
    const float* emb   = (const float*)d_in[3];
    const float* w_ih  = (const float*)d_in[4];
    const float* w_hh  = (const float*)d_in[5];
    const float* b_ih  = (const float*)d_in[6];
    const float* b_hh  = (const float*)d_in[7];
    const float* L1    = (const float*)d_in[8];
    const float* L2    = (const float*)d_in[9];

    float* out = (float*)d_out;                         // (T,B,HID) + (2,B,HID)

    // ---- ws plan (bump allocator) ----
    char* basep = (char*)d_ws;
    size_t off = 0;
    auto alloc = [&](size_t bytes) -> char* {
        off = (off + 255) & ~(size_t)255;
        char* p = basep + off; off += bytes; return p;
    };
    short* wih0h = (short*)alloc(3072L*1024*2); short* wih0l = (short*)alloc(3072L*1024*2);
    short* whh0h = (short*)alloc(3072L*1024*2); short* whh0l = (short*)alloc(3072L*1024*2);
    short* wih1h = (short*)alloc(3072L*1024*2); short* wih1l = (short*)alloc(3072L*1024*2);
    short* whh1h = (short*)alloc(3072L*1024*2); short* whh1l = (short*)alloc(3072L*1024*2);
    short* l1h   = (short*)alloc(1024L*1024*2); short* l1l   = (short*)alloc(1024L*1024*2);
    short* l2h   = (short*)alloc(1024L*2048*2); short* l2l   = (short*)alloc(1024L*2048*2);
    short* Hh    = (short*)alloc(16777216L*2);  short* Hl    = (short*)alloc(16777216L*2);
    short* hih   = (short*)alloc(262144L*2);    short* hil   = (short*)alloc(262144L*2);
    short* h0ah  = (short*)alloc(8388608L*2);   short* h0al  = (short*)alloc(8388608L*2);
    short* h1ah  = (short*)alloc(8388608L*2);   short* h1al  = (short*)alloc(8388608L*2);
    short* eqh   = (short*)alloc(8388608L*2);   short* eql   = (short*)alloc(8388608L*2);
    float* gi0   = (float*)alloc(25165824L*4);  // gi0 / gi1 / ctx-planes (lifetimes disjoint)
    float* h0f   = (float*)alloc(262144L*4);
    float* h1f   = (float*)alloc(8388608L*4);
    float* Pall  = (float*)alloc(1048576L*4);
    float* gi1   = gi0;                  // gi0 dead after phase 1
    short* ctxh  = (short*)gi0;          // gi1 dead after phase 2
    short* ctxl  = ctxh + 8388608L;

    const dim3 blk(256);
    const size_t SM3 = (2 * 8192 + 2 * 3 * 2048) * sizeof(short);  // 57344
    const size_t SM1 = (2 * 8192 + 2 * 1 * 2048) * sizeof(short);  // 40960

    // ---- phase 0: plane conversions ----
    conv_planes_k<<<1536, blk, 0, stream>>>(w_ih, wih0h, wih0l);
    conv_planes_k<<<1536, blk, 0, stream>>>(w_hh, whh0h, whh0l);
    conv_planes_k<<<1536, blk, 0, stream>>>(w_ih + (size_t)H3 * EMBD, wih1h, wih1l);
    conv_planes_k<<<1536, blk, 0, stream>>>(w_hh + (size_t)H3 * HID, whh1h, whh1l);
    conv_planes_k<<<512,  blk, 0, stream>>>(L1, l1h, l1l);
    conv_planes_k<<<1024, blk, 0, stream>>>(L2, l2h, l2l);
    conv_planes_k<<<8192, blk, 0, stream>>>(Hbuf, Hh, Hl);
    conv_planes_k<<<128,  blk, 0, stream>>>(h_in, hih, hil);
    conv_gather_k<<<4096, blk, 0, stream>>>(emb, input, eqh, eql);

    // gi0_all = E @ w_ih0^T + b_ih0   (8192 x 3072)
    gemm_ps<3, 0, false><<<dim3(128, 64), blk, SM3, stream>>>(
        eqh, eql, nullptr, nullptr, wih0h, wih0l, 1024,
        b_ih, nullptr, nullptr, nullptr, gi0, nullptr, nullptr, H3);

    // ---- phase 1: h0 recurrence ----
    for (int t = 0; t < T_STEPS; ++t) {
        const short* a1h = t ? h0ah + (long)(t - 1) * BH : hih;
        const short* a1l = t ? h0al + (long)(t - 1) * BH : hil;
        const float* hp  = t ? h0f + (long)((t - 1) & 1) * BH : h_in;
        gemm_ps<3, 2, false><<<dim3(2, 64), blk, SM3, stream>>>(
            a1h, a1l, nullptr, nullptr, whh0h, whh0l, 1024,
            b_hh, nullptr, gi0 + (long)t * BATCH * H3, hp,
            h0f + (long)(t & 1) * BH, h0ah + (long)t * BH, h0al + (long)t * BH, HID);
    }

    // gi1_all = h0_all @ w_ih1^T + b_ih1   (8192 x 3072; reuses gi0 buffer)
    gemm_ps<3, 0, false><<<dim3(128, 64), blk, SM3, stream>>>(
        h0ah, h0al, nullptr, nullptr, wih1h, wih1l, 1024,
        b_ih + H3, nullptr, nullptr, nullptr, gi1, nullptr, nullptr, H3);

    // ---- phase 2: h1 recurrence (K=1024, gi precomputed) ----
    for (int t = 0; t < T_STEPS; ++t) {
        const short* a2h = t ? h1ah + (long)(t - 1) * BH : hih + BH;
        const short* a2l = t ? h1al + (long)(t - 1) * BH : hil + BH;
        const float* hp  = t ? h1f + (long)(t - 1) * BH : h_in + BH;
        gemm_ps<3, 2, false><<<dim3(2, 64), blk, SM3, stream>>>(
            a2h, a2l, nullptr, nullptr, whh1h, whh1l, 1024,
            b_hh + H3, nullptr, gi1 + (long)t * BATCH * H3, hp,
            h1f + (long)t * BH, h1ah + (long)t * BH, h1al + (long)t * BH, HID);
    }

    // ---- phase 3: batched attention + output ----
    gemm_ps<1, 1, false><<<dim3(128, 64), blk, SM1, stream>>>(
        h1ah, h1al, nullptr, nullptr, l1h, l1l, 1024,
        nullptr, nullptr, nullptr, nullptr, nullptr, eqh, eql, HID);
    scores_k<<<dim3(BATCH), blk, 49152, stream>>>(eqh, eql, Hh, Hl, Pall);
    ctx_k<<<dim3(BATCH, 4), blk, 0, stream>>>(Pall, Hbuf, ctxh, ctxl);
    gemm_ps<1, 4, true><<<dim3(128, 64), blk, SM1, stream>>>(
        ctxh, ctxl, h1ah, h1al, l2h, l2l, 2048,
        nullptr, nullptr, nullptr, nullptr, out, nullptr, nullptr, HID);

    hipMemcpyAsync(out + (long)T_STEPS * BH, h0f + BH, (size_t)BH * 4,
                   hipMemcpyDeviceToDevice, stream);
    hipMemcpyAsync(out + (long)T_STEPS * BH + BH, h1f + 63L * BH, (size_t)BH * 4,
                   hipMemcpyDeviceToDevice, stream);
}

// Round 5
// 2689.873 us; speedup vs baseline: 7.4331x; 1.5219x over previous
//
#include <hip/hip_runtime.h>

#define T_STEPS 64
#define BATCH   128
#define HID     1024
#define H3      3072
#define EMBD    1024
#define SLEN    128
#define BH      (BATCH * HID)

typedef __attribute__((ext_vector_type(8))) short short8;
typedef __attribute__((ext_vector_type(4))) float f32x4;

__device__ __forceinline__ unsigned short f2bf(float x) {
    unsigned int u = __float_as_uint(x);
    unsigned int r = (u + 0x7fffu + ((u >> 16) & 1u)) >> 16;
    return (unsigned short)r;
}
__device__ __forceinline__ float bf2f(unsigned short h) {
    return __uint_as_float(((unsigned int)h) << 16);
}
__device__ __forceinline__ unsigned int pk(unsigned short a, unsigned short b) {
    return (unsigned int)a | ((unsigned int)b << 16);
}
__device__ __forceinline__ void cvt8(const float4& x, const float4& y,
                                     uint4& H, uint4& L) {
    unsigned short h0 = f2bf(x.x), h1 = f2bf(x.y), h2 = f2bf(x.z), h3 = f2bf(x.w);
    unsigned short h4 = f2bf(y.x), h5 = f2bf(y.y), h6 = f2bf(y.z), h7 = f2bf(y.w);
    unsigned short l0 = f2bf(x.x - bf2f(h0)), l1 = f2bf(x.y - bf2f(h1));
    unsigned short l2 = f2bf(x.z - bf2f(h2)), l3 = f2bf(x.w - bf2f(h3));
    unsigned short l4 = f2bf(y.x - bf2f(h4)), l5 = f2bf(y.y - bf2f(h5));
    unsigned short l6 = f2bf(y.z - bf2f(h6)), l7 = f2bf(y.w - bf2f(h7));
    H = make_uint4(pk(h0,h1), pk(h2,h3), pk(h4,h5), pk(h6,h7));
    L = make_uint4(pk(l0,l1), pk(l2,l3), pk(l4,l5), pk(l6,l7));
}
__device__ __forceinline__ float sigf(float x) {
    return 1.f / (1.f + __expf(-x));
}

#define TRI(AH, AL, WH, WL, ACC)                                                \
    ACC = __builtin_amdgcn_mfma_f32_16x16x32_bf16(AH, WL, ACC, 0, 0, 0);        \
    ACC = __builtin_amdgcn_mfma_f32_16x16x32_bf16(AL, WH, ACC, 0, 0, 0);        \
    ACC = __builtin_amdgcn_mfma_f32_16x16x32_bf16(AH, WH, ACC, 0, 0, 0);

// ============== plane-conversion kernels (run once per call) ==============
__global__ __launch_bounds__(256) void conv_planes_k(
    const float* __restrict__ src, short* __restrict__ hi, short* __restrict__ lo)
{
    const long i8 = (long)blockIdx.x * 256 + threadIdx.x;
    float4 x = ((const float4*)src)[i8 * 2];
    float4 y = ((const float4*)src)[i8 * 2 + 1];
    uint4 H, L; cvt8(x, y, H, L);
    ((uint4*)hi)[i8] = H; ((uint4*)lo)[i8] = L;
}

// gathered embedding rows -> planes (8192 x 1024)
__global__ __launch_bounds__(256) void conv_gather_k(
    const float* __restrict__ emb, const int* __restrict__ input,
    short* __restrict__ hi, short* __restrict__ lo)
{
    const long i8 = (long)blockIdx.x * 256 + threadIdx.x;
    const int c8 = (int)(i8 & 127);
    const long row = i8 >> 7;
    const float* s = emb + (size_t)input[row] * 1024 + c8 * 8;
    float4 x = ((const float4*)s)[0];
    float4 y = ((const float4*)s)[1];
    uint4 H, L; cvt8(x, y, H, L);
    ((uint4*)hi)[i8] = H; ((uint4*)lo)[i8] = L;
}

// ============== big batched GEMM: 128x128 block tile ==============
// C = A(M x K) @ W(N x K)^T, bf16 hi/lo planes. 256 thr = 4 waves in 2x2
// quadrants; each wave owns 64x64 (4x4 16x16 frags). BK=32, double-buffered
// LDS, linear fragment-major maps (conflict-free), 2-deep prefetch,
// XCD-bijective block swizzle (1-D grid, nwg % 8 == 0).
// MODE 0: outf = acc + bias[col]     MODE 1: plane store    MODE 2: tanh store
template<int MODE, bool CONCAT>
__global__ __launch_bounds__(256, 2) void gemm_big(
    const short* __restrict__ A1h, const short* __restrict__ A1l,
    const short* __restrict__ A2h, const short* __restrict__ A2l,
    const short* __restrict__ Wh,  const short* __restrict__ Wl,
    int K, int nn,
    const float* __restrict__ bias,
    float* __restrict__ outf, short* __restrict__ outh, short* __restrict__ outl,
    int ldo)
{
    extern __shared__ short sm[];
    short* Asm = sm;               // 2 buf x 8192 shorts (hi 0..4095 | lo 4096..)
    short* Wsm = sm + 16384;       // 2 buf x 8192 shorts
    const int tid = threadIdx.x;
    const int wv = tid >> 6, l = tid & 63;
    const int mq = wv >> 1, nq = wv & 1;
    const int gl = l >> 4, r16 = l & 15;

    const int cpx = gridDim.x >> 3;
    const int id = blockIdx.x;
    const int swz = (id & 7) * cpx + (id >> 3);
    const int bm = swz / nn, bn = swz % nn;
    const long Rbase = (long)bm * 128;
    const int  Cbase = bn * 128;

    const int lda = CONCAT ? (K >> 1) : K;
    const int NC = K >> 5;
    const int NCh = NC >> 1;

    // staging maps: slot s -> (plane, row, kgroup); 4 A + 4 W slots per thread
    const short *aP1[4], *aP2[4], *wP[4];
    int slda[4];
    #pragma unroll
    for (int j = 0; j < 4; ++j) {
        const int s = tid + j * 256;
        const int pl = s >> 9, sp = s & 511;
        const int row = ((sp >> 6) << 4) | (sp & 15);
        const int kg = (sp >> 4) & 3;
        slda[j] = s * 8;
        const short* a1 = pl ? A1l : A1h;
        aP1[j] = a1 + (Rbase + row) * (long)lda + kg * 8;
        if (CONCAT) {
            const short* a2 = pl ? A2l : A2h;
            aP2[j] = a2 + (Rbase + row) * (long)lda + kg * 8;
        } else aP2[j] = aP1[j];
        const short* wp = pl ? Wl : Wh;
        wP[j] = wp + ((long)Cbase + row) * (long)K + kg * 8;
    }

    f32x4 acc[4][4];
    #pragma unroll
    for (int i = 0; i < 4; ++i)
        #pragma unroll
        for (int j = 0; j < 4; ++j) acc[i][j] = (f32x4)0.f;

    short8 rA[4], rW[4];
    auto LOADC = [&](int c) {
        const bool p1 = !CONCAT || (c < NCh);
        const long ko = p1 ? (long)c * 32 : (long)c * 32 - (K >> 1);
        #pragma unroll
        for (int j = 0; j < 4; ++j) {
            rA[j] = *(const short8*)((p1 ? aP1[j] : aP2[j]) + ko);
            rW[j] = *(const short8*)(wP[j] + (long)c * 32);
        }
    };
    auto STORE = [&](int c) {
        const int b = (c & 1) << 13;
        #pragma unroll
        for (int j = 0; j < 4; ++j) {
            *(short8*)(Asm + b + slda[j]) = rA[j];
            *(short8*)(Wsm + b + slda[j]) = rW[j];
        }
    };

    LOADC(0); STORE(0); LOADC(1);
    __syncthreads();

    for (int c = 0; c < NC; ++c) {
        const int b = (c & 1) << 13;
        short8 ah[4], al[4], wh[4], wl[4];
        #pragma unroll
        for (int f = 0; f < 4; ++f) {
            const short* ab = Asm + b + ((mq * 4 + f) * 64 + l) * 8;
            ah[f] = *(const short8*)ab;
            al[f] = *(const short8*)(ab + 4096);
            const short* wb = Wsm + b + ((nq * 4 + f) * 64 + l) * 8;
            wh[f] = *(const short8*)wb;
            wl[f] = *(const short8*)(wb + 4096);
        }
        if (c + 1 < NC) STORE(c + 1);
        if (c + 2 < NC) LOADC(c + 2);
        #pragma unroll
        for (int mf = 0; mf < 4; ++mf)
            #pragma unroll
            for (int nf = 0; nf < 4; ++nf) {
                TRI(ah[mf], al[mf], wh[nf], wl[nf], acc[mf][nf]);
            }
        __syncthreads();
    }

    #pragma unroll
    for (int mf = 0; mf < 4; ++mf) {
        #pragma unroll
        for (int reg = 0; reg < 4; ++reg) {
            const long R = Rbase + mq * 64 + mf * 16 + gl * 4 + reg;
            #pragma unroll
            for (int nf = 0; nf < 4; ++nf) {
                const int col = Cbase + nq * 64 + nf * 16 + r16;
                const float v = acc[mf][nf][reg];
                if constexpr (MODE == 0) {
                    outf[R * (long)ldo + col] = v + bias[col];
                } else if constexpr (MODE == 1) {
                    const unsigned short hi = f2bf(v), lo = f2bf(v - bf2f(hi));
                    outh[R * (long)ldo + col] = (short)hi;
                    outl[R * (long)ldo + col] = (short)lo;
                } else {
                    outf[R * (long)ldo + col] = tanhf(v);
                }
            }
        }
    }
}

// ============== recurrence GEMM (pre-split planes, gate epilogue) ==============
// WLO: drop the W lo-plane (skip Ah*Wl term) -> halved W traffic, 12 MFMA/chunk.
template<int P, int MODE, bool CONCAT, bool WLO>
__global__ __launch_bounds__(256) void gemm_ps(
    const short* __restrict__ A1h, const short* __restrict__ A1l,
    const short* __restrict__ A2h, const short* __restrict__ A2l,
    const short* __restrict__ Wh,  const short* __restrict__ Wl,
    int K,
    const float* __restrict__ bias, const float* __restrict__ bias2,
    const float* __restrict__ other, const float* __restrict__ hprev,
    float* __restrict__ outf, short* __restrict__ outh, short* __restrict__ outl,
    int ldo)
{
    extern __shared__ short sm[];
    const int ABUF = 8192, WBUF = P * 2048;
    short* Asm = sm;
    short* Wsm = sm + 2 * ABUF;
    const int tid = threadIdx.x;
    const int wv = tid >> 6, l = tid & 63;
    const int gl = l >> 4, r16 = l & 15;
    const int bm = blockIdx.x, bj = blockIdx.y;

    const int NC = K >> 6;
    const int NC_half = NC >> 1;

    const short *a1hP[2], *a1lP[2], *a2hP[2], *a2lP[2];
    int aLds[2];
    const int ldA = CONCAT ? (K >> 1) : K;
    #pragma unroll
    for (int i = 0; i < 2; ++i) {
        const int s = tid + i * 256;
        const int row = ((s >> 6) & 3) * 16 + (s & 15);
        const int kg  = ((s >> 8) << 2) | ((s >> 4) & 3);
        const long r = (long)bm * 64 + row;
        a1hP[i] = A1h + r * ldA + kg * 8;
        a1lP[i] = A1l + r * ldA + kg * 8;
        if (CONCAT) {
            a2hP[i] = A2h + r * (K >> 1) + kg * 8;
            a2lP[i] = A2l + r * (K >> 1) + kg * 8;
        } else { a2hP[i] = a1hP[i]; a2lP[i] = a1lP[i]; }
        aLds[i] = s * 8;
    }
    const bool doW = tid < P * 64;
    const short *whP[2], *wlP[2];
    int wLds[2] = {0, 0};
    if (doW) {
        #pragma unroll
        for (int i = 0; i < 2; ++i) {
            const int s = tid + i * P * 64;
            const int kcw = s / (P * 64);
            const int rem = s - kcw * (P * 64);
            const int p = rem >> 6, ll = rem & 63;
            const int jr = ll & 15, g = ll >> 4;
            const int kg = kcw * 4 + g;
            const long grow = (long)(p << 10) + bj * 16 + jr;
            whP[i] = Wh + grow * K + kg * 8;
            wlP[i] = Wl + grow * K + kg * 8;
            wLds[i] = s * 8;
        }
    }

    f32x4 acc[P];
    #pragma unroll
    for (int i = 0; i < P; ++i) acc[i] = (f32x4)0.f;

    short8 rAh[2], rAl[2], rWh[2], rWl[2];
    auto LOADC = [&](int c) {
        const bool part1 = !CONCAT || (c < NC_half);
        const long ko = part1 ? (long)c * 64 : (long)c * 64 - (K >> 1);
        #pragma unroll
        for (int i = 0; i < 2; ++i) {
            rAh[i] = *(const short8*)((part1 ? a1hP[i] : a2hP[i]) + ko);
            rAl[i] = *(const short8*)((part1 ? a1lP[i] : a2lP[i]) + ko);
        }
        if (doW) {
            #pragma unroll
            for (int i = 0; i < 2; ++i) {
                rWh[i] = *(const short8*)(whP[i] + (long)c * 64);
                if (!WLO) rWl[i] = *(const short8*)(wlP[i] + (long)c * 64);
            }
        }
    };
    auto STORE = [&](int c) {
        const int b = c & 1;
        #pragma unroll
        for (int i = 0; i < 2; ++i) {
            *(short8*)(Asm + b * ABUF + aLds[i]) = rAh[i];
            *(short8*)(Asm + b * ABUF + 4096 + aLds[i]) = rAl[i];
        }
        if (doW) {
            #pragma unroll
            for (int i = 0; i < 2; ++i) {
                *(short8*)(Wsm + b * WBUF + wLds[i]) = rWh[i];
                if (!WLO) *(short8*)(Wsm + b * WBUF + P * 1024 + wLds[i]) = rWl[i];
            }
        }
    };

    LOADC(0); STORE(0); LOADC(1);
    __syncthreads();

    for (int c = 0; c < NC; ++c) {
        const int b = c & 1;
        short8 fah[2], fal[2], fwh[2][P], fwl[2][P];
        #pragma unroll
        for (int kc = 0; kc < 2; ++kc) {
            const short* ab = Asm + b * ABUF + (kc * 256 + wv * 64 + l) * 8;
            fah[kc] = *(const short8*)ab;
            fal[kc] = *(const short8*)(ab + 4096);
            #pragma unroll
            for (int p = 0; p < P; ++p) {
                const short* wb = Wsm + b * WBUF + (kc * (P * 64) + p * 64 + l) * 8;
                fwh[kc][p] = *(const short8*)wb;
                if (!WLO) fwl[kc][p] = *(const short8*)(wb + P * 1024);
            }
        }
        if (c + 1 < NC) STORE(c + 1);
        if (c + 2 < NC) LOADC(c + 2);
        #pragma unroll
        for (int kc = 0; kc < 2; ++kc) {
            #pragma unroll
            for (int p = 0; p < P; ++p) {
                if constexpr (WLO) {
                    acc[p] = __builtin_amdgcn_mfma_f32_16x16x32_bf16(fal[kc], fwh[kc][p], acc[p], 0, 0, 0);
                    acc[p] = __builtin_amdgcn_mfma_f32_16x16x32_bf16(fah[kc], fwh[kc][p], acc[p], 0, 0, 0);
                } else {
                    TRI(fah[kc], fal[kc], fwh[kc][p], fwl[kc][p], acc[p]);
                }
            }
        }
        __syncthreads();
    }

    const int jc = bj * 16 + r16;
    #pragma unroll
    for (int reg = 0; reg < 4; ++reg) {
        const long R = (long)bm * 64 + wv * 16 + gl * 4 + reg;
        if constexpr (MODE == 0) {
            #pragma unroll
            for (int p = 0; p < P; ++p)
                outf[R * ldo + p * 1024 + jc] = acc[p][reg] + bias[p * 1024 + jc];
        } else if constexpr (MODE == 2) {
            const float* orow = other + R * H3;
            const float rr = sigf(orow[jc] + acc[0][reg] + bias[jc]);
            const float zz = sigf(orow[HID + jc] + acc[1][reg] + bias[HID + jc]);
            const float nn = tanhf(orow[2 * HID + jc] + rr * (acc[2][reg] + bias[2 * HID + jc]));
            const float h = (1.f - zz) * nn + zz * hprev[R * HID + jc];
            outf[R * HID + jc] = h;
            const unsigned short hi = f2bf(h), lo = f2bf(h - bf2f(hi));
            outh[R * HID + jc] = (short)hi; outl[R * HID + jc] = (short)lo;
        }
    }
}

// ============== batched attention scores + softmax (per b) ==============
__global__ __launch_bounds__(256) void scores_k(
    const short* __restrict__ Qh, const short* __restrict__ Ql,
    const short* __restrict__ Hh, const short* __restrict__ Hl,
    float* __restrict__ Pall)
{
    extern __shared__ short sm[];
    short* Asm = sm;
    short* Wsm = sm + 8192;
    const int b = blockIdx.x, tid = threadIdx.x;
    const int wv = tid >> 6, l = tid & 63;
    const int gl = l >> 4, cc = l & 15;

    const int arow = ((tid >> 6) & 3) * 16 + (tid & 15);
    const int ag   = (tid >> 4) & 3;
    const short* qhp = Qh + ((long)arow * BATCH + b) * HID + ag * 8;
    const short* qlp = Ql + ((long)arow * BATCH + b) * HID + ag * 8;
    const int aLds = tid * 8;

    const short *whp[2], *wlp[2]; int wLds[2];
    #pragma unroll
    for (int i = 0; i < 2; ++i) {
        const int s = tid + i * 256;
        const int srow = ((s >> 6) & 7) * 16 + (s & 15);
        const int sg   = (s >> 4) & 3;
        whp[i] = Hh + ((long)srow * BATCH + b) * HID + sg * 8;
        wlp[i] = Hl + ((long)srow * BATCH + b) * HID + sg * 8;
        wLds[i] = s * 8;
    }

    f32x4 acc[8];
    #pragma unroll
    for (int i = 0; i < 8; ++i) acc[i] = (f32x4)0.f;

    short8 rAh, rAl, rWh[2], rWl[2];
    auto LOADC = [&](int c) {
        rAh = *(const short8*)(qhp + c * 32);
        rAl = *(const short8*)(qlp + c * 32);
        #pragma unroll
        for (int i = 0; i < 2; ++i) {
            rWh[i] = *(const short8*)(whp[i] + c * 32);
            rWl[i] = *(const short8*)(wlp[i] + c * 32);
        }
    };
    auto STORE = [&](int c) {
        const int bb = c & 1;
        *(short8*)(Asm + bb * 4096 + aLds) = rAh;
        *(short8*)(Asm + bb * 4096 + 2048 + aLds) = rAl;
        #pragma unroll
        for (int i = 0; i < 2; ++i) {
            *(short8*)(Wsm + bb * 8192 + wLds[i]) = rWh[i];
            *(short8*)(Wsm + bb * 8192 + 4096 + wLds[i]) = rWl[i];
        }
    };

    LOADC(0); STORE(0); LOADC(1);
    __syncthreads();
    for (int c = 0; c < 32; ++c) {
        const int bb = c & 1;
        const short* abp = Asm + bb * 4096 + (wv * 64 + l) * 8;
        short8 ah = *(const short8*)abp;
        short8 al = *(const short8*)(abp + 2048);
        if (c + 1 < 32) STORE(c + 1);
        if (c + 2 < 32) LOADC(c + 2);
        #pragma unroll
        for (int jt = 0; jt < 8; ++jt) {
            const short* wbp = Wsm + bb * 8192 + (jt * 64 + l) * 8;
            short8 wh = *(const short8*)wbp;
            short8 wl = *(const short8*)(wbp + 4096);
            TRI(ah, al, wh, wl, acc[jt]);
        }
        __syncthreads();
    }

    #pragma unroll
    for (int reg = 0; reg < 4; ++reg) {
        float m = acc[0][reg];
        #pragma unroll
        for (int jt = 1; jt < 8; ++jt) m = fmaxf(m, acc[jt][reg]);
        #pragma unroll
        for (int off = 1; off < 16; off <<= 1) m = fmaxf(m, __shfl_xor(m, off));
        float e[8], ssum = 0.f;
        #pragma unroll
        for (int jt = 0; jt < 8; ++jt) { e[jt] = __expf(acc[jt][reg] - m); ssum += e[jt]; }
        #pragma unroll
        for (int off = 1; off < 16; off <<= 1) ssum += __shfl_xor(ssum, off);
        const float inv = 1.f / ssum;
        const int t = wv * 16 + gl * 4 + reg;
        #pragma unroll
        for (int jt = 0; jt < 8; ++jt)
            Pall[((long)t * BATCH + b) * SLEN + jt * 16 + cc] = e[jt] * inv;
    }
}

// context[t,b,col] = sum_s P[t,s] * H[s,b,col]; writes ctx planes.
__global__ __launch_bounds__(256) void ctx_k(
    const float* __restrict__ Pall, const float* __restrict__ H,
    short* __restrict__ Ch, short* __restrict__ Cl)
{
    __shared__ float Ps[T_STEPS * SLEN];
    const int b = blockIdx.x, ht = blockIdx.y, tid = threadIdx.x;
    for (int i = 0; i < 32; ++i) {
        const int idx = i * 256 + tid;
        const int t = idx >> 7, s = idx & 127;
        Ps[idx] = Pall[((long)t * BATCH + b) * SLEN + s];
    }
    __syncthreads();
    const int col = ht * 256 + tid;
    for (int tg = 0; tg < 4; ++tg) {
        float a[16];
        #pragma unroll
        for (int j = 0; j < 16; ++j) a[j] = 0.f;
        for (int s = 0; s < SLEN; ++s) {
            const float hv = H[((long)s * BATCH + b) * HID + col];
            #pragma unroll
            for (int j = 0; j < 16; ++j)
                a[j] = fmaf(Ps[(tg * 16 + j) * SLEN + s], hv, a[j]);
        }
        #pragma unroll
        for (int j = 0; j < 16; ++j) {
            const long row = (long)(tg * 16 + j) * BATCH + b;
            const unsigned short hi = f2bf(a[j]);
            const unsigned short lo = f2bf(a[j] - bf2f(hi));
            Ch[row * HID + col] = (short)hi;
            Cl[row * HID + col] = (short)lo;
        }
    }
}

// =========================== launch ===========================
extern "C" void kernel_launch(void* const* d_in, const int* in_sizes, int n_in,
                              void* d_out, int out_size, void* d_ws, size_t ws_size,
                              hipStream_t stream)
{
    const int*   input = (const int*)  d_in[0];
    const float* h_in  = (const float*)d_in[1];
    const float* Hbuf  = (const float*)d_in[2];
    const float* emb   = (const float*)d_in[3];
    const float* w_ih  = (const float*)d_in[4];
    const float* w_hh  = (const float*)d_in[5];
    const float* b_ih  = (const float*)d_in[6];
    const float* b_hh  = (const float*)d_in[7];
    const float* L1    = (const float*)d_in[8];
    const float* L2    = (const float*)d_in[9];

    float* out = (float*)d_out;

    char* basep = (char*)d_ws;
    size_t off = 0;
    auto alloc = [&](size_t bytes) -> char* {
        off = (off + 255) & ~(size_t)255;
        char* p = basep + off; off += bytes; return p;
    };
    short* wih0h = (short*)alloc(3072L*1024*2); short* wih0l = (short*)alloc(3072L*1024*2);
    short* whh0h = (short*)alloc(3072L*1024*2); short* whh0l = (short*)alloc(3072L*1024*2);
    short* wih1h = (short*)alloc(3072L*1024*2); short* wih1l = (short*)alloc(3072L*1024*2);
    short* whh1h = (short*)alloc(3072L*1024*2); short* whh1l = (short*)alloc(3072L*1024*2);
    short* l1h   = (short*)alloc(1024L*1024*2); short* l1l   = (short*)alloc(1024L*1024*2);
    short* l2h   = (short*)alloc(1024L*2048*2); short* l2l   = (short*)alloc(1024L*2048*2);
    short* Hh    = (short*)alloc(16777216L*2);  short* Hl    = (short*)alloc(16777216L*2);
    short* hih   = (short*)alloc(262144L*2);    short* hil   = (short*)alloc(262144L*2);
    short* h0ah  = (short*)alloc(8388608L*2);   short* h0al  = (short*)alloc(8388608L*2);
    short* h1ah  = (short*)alloc(8388608L*2);   short* h1al  = (short*)alloc(8388608L*2);
    short* eqh   = (short*)alloc(8388608L*2);   short* eql   = (short*)alloc(8388608L*2);
    float* gi0   = (float*)alloc(25165824L*4);
    float* h0f   = (float*)alloc(262144L*4);
    float* h1f   = (float*)alloc(8388608L*4);
    float* Pall  = (float*)alloc(1048576L*4);
    float* gi1   = gi0;
    short* ctxh  = (short*)gi0;
    short* ctxl  = ctxh + 8388608L;

    const dim3 blk(256);
    const size_t SMB = 32768 * sizeof(short);                      // 65536
    const size_t SM3 = (2 * 8192 + 2 * 3 * 2048) * sizeof(short);  // 57344

    // ---- phase 0: plane conversions ----
    conv_planes_k<<<1536, blk, 0, stream>>>(w_ih, wih0h, wih0l);
    conv_planes_k<<<1536, blk, 0, stream>>>(w_hh, whh0h, whh0l);
    conv_planes_k<<<1536, blk, 0, stream>>>(w_ih + (size_t)H3 * EMBD, wih1h, wih1l);
    conv_planes_k<<<1536, blk, 0, stream>>>(w_hh + (size_t)H3 * HID, whh1h, whh1l);
    conv_planes_k<<<512,  blk, 0, stream>>>(L1, l1h, l1l);
    conv_planes_k<<<1024, blk, 0, stream>>>(L2, l2h, l2l);
    conv_planes_k<<<8192, blk, 0, stream>>>(Hbuf, Hh, Hl);
    conv_planes_k<<<128,  blk, 0, stream>>>(h_in, hih, hil);
    conv_gather_k<<<4096, blk, 0, stream>>>(emb, input, eqh, eql);

    // gi0_all = E @ w_ih0^T + b_ih0   (8192 x 3072 x 1024)
    gemm_big<0, false><<<dim3(1536), blk, SMB, stream>>>(
        eqh, eql, nullptr, nullptr, wih0h, wih0l, 1024, 24,
        b_ih, gi0, nullptr, nullptr, H3);

    // ---- phase 1: h0 recurrence ----
    for (int t = 0; t < T_STEPS; ++t) {
        const short* a1h = t ? h0ah + (long)(t - 1) * BH : hih;
        const short* a1l = t ? h0al + (long)(t - 1) * BH : hil;
        const float* hp  = t ? h0f + (long)((t - 1) & 1) * BH : h_in;
        gemm_ps<3, 2, false, true><<<dim3(2, 64), blk, SM3, stream>>>(
            a1h, a1l, nullptr, nullptr, whh0h, whh0l, 1024,
            b_hh, nullptr, gi0 + (long)t * BATCH * H3, hp,
            h0f + (long)(t & 1) * BH, h0ah + (long)t * BH, h0al + (long)t * BH, HID);
    }

    // gi1_all = h0_all @ w_ih1^T + b_ih1   (reuses gi0 buffer)
    gemm_big<0, false><<<dim3(1536), blk, SMB, stream>>>(
        h0ah, h0al, nullptr, nullptr, wih1h, wih1l, 1024, 24,
        b_ih + H3, gi1, nullptr, nullptr, H3);

    // ---- phase 2: h1 recurrence ----
    for (int t = 0; t < T_STEPS; ++t) {
        const short* a2h = t ? h1ah + (long)(t - 1) * BH : hih + BH;
        const short* a2l = t ? h1al + (long)(t - 1) * BH : hil + BH;
        const float* hp  = t ? h1f + (long)(t - 1) * BH : h_in + BH;
        gemm_ps<3, 2, false, true><<<dim3(2, 64), blk, SM3, stream>>>(
            a2h, a2l, nullptr, nullptr, whh1h, whh1l, 1024,
            b_hh + H3, nullptr, gi1 + (long)t * BATCH * H3, hp,
            h1f + (long)t * BH, h1ah + (long)t * BH, h1al + (long)t * BH, HID);
    }

    // ---- phase 3: batched attention + output ----
    gemm_big<1, false><<<dim3(512), blk, SMB, stream>>>(
        h1ah, h1al, nullptr, nullptr, l1h, l1l, 1024, 8,
        nullptr, nullptr, eqh, eql, HID);
    scores_k<<<dim3(BATCH), blk, 49152, stream>>>(eqh, eql, Hh, Hl, Pall);
    ctx_k<<<dim3(BATCH, 4), blk, 0, stream>>>(Pall, Hbuf, ctxh, ctxl);
    gemm_big<2, true><<<dim3(512), blk, SMB, stream>>>(
        ctxh, ctxl, h1ah, h1al, l2h, l2l, 2048, 8,
        nullptr, out, nullptr, nullptr, HID);

    hipMemcpyAsync(out + (long)T_STEPS * BH, h0f + BH, (size_t)BH * 4,
                   hipMemcpyDeviceToDevice, stream);
    hipMemcpyAsync(out + (long)T_STEPS * BH + BH, h1f + 63L * BH, (size_t)BH * 4,
                   hipMemcpyDeviceToDevice, stream);
}

// Round 6
// 2295.132 us; speedup vs baseline: 8.7115x; 1.1720x over previous
//
#include <hip/hip_runtime.h>

#define T_STEPS 64
#define BATCH   128
#define HID     1024
#define H3      3072
#define EMBD    1024
#define SLEN    128
#define BH      (BATCH * HID)

typedef __attribute__((ext_vector_type(8))) short short8;
typedef __attribute__((ext_vector_type(4))) float f32x4;

__device__ __forceinline__ unsigned short f2bf(float x) {
    unsigned int u = __float_as_uint(x);
    unsigned int r = (u + 0x7fffu + ((u >> 16) & 1u)) >> 16;
    return (unsigned short)r;
}
__device__ __forceinline__ float bf2f(unsigned short h) {
    return __uint_as_float(((unsigned int)h) << 16);
}
__device__ __forceinline__ unsigned int pk(unsigned short a, unsigned short b) {
    return (unsigned int)a | ((unsigned int)b << 16);
}
__device__ __forceinline__ void cvt8(const float4& x, const float4& y,
                                     uint4& H, uint4& L) {
    unsigned short h0 = f2bf(x.x), h1 = f2bf(x.y), h2 = f2bf(x.z), h3 = f2bf(x.w);
    unsigned short h4 = f2bf(y.x), h5 = f2bf(y.y), h6 = f2bf(y.z), h7 = f2bf(y.w);
    unsigned short l0 = f2bf(x.x - bf2f(h0)), l1 = f2bf(x.y - bf2f(h1));
    unsigned short l2 = f2bf(x.z - bf2f(h2)), l3 = f2bf(x.w - bf2f(h3));
    unsigned short l4 = f2bf(y.x - bf2f(h4)), l5 = f2bf(y.y - bf2f(h5));
    unsigned short l6 = f2bf(y.z - bf2f(h6)), l7 = f2bf(y.w - bf2f(h7));
    H = make_uint4(pk(h0,h1), pk(h2,h3), pk(h4,h5), pk(h6,h7));
    L = make_uint4(pk(l0,l1), pk(l2,l3), pk(l4,l5), pk(l6,l7));
}
__device__ __forceinline__ float sigf(float x) {
    return 1.f / (1.f + __expf(-x));
}

#define TRI(AH, AL, WH, WL, ACC)                                                \
    ACC = __builtin_amdgcn_mfma_f32_16x16x32_bf16(AH, WL, ACC, 0, 0, 0);        \
    ACC = __builtin_amdgcn_mfma_f32_16x16x32_bf16(AL, WH, ACC, 0, 0, 0);        \
    ACC = __builtin_amdgcn_mfma_f32_16x16x32_bf16(AH, WH, ACC, 0, 0, 0);
#define DUO(AH, AL, WH, ACC)                                                    \
    ACC = __builtin_amdgcn_mfma_f32_16x16x32_bf16(AL, WH, ACC, 0, 0, 0);        \
    ACC = __builtin_amdgcn_mfma_f32_16x16x32_bf16(AH, WH, ACC, 0, 0, 0);

// ============== plane-conversion kernels (run once per call) ==============
__global__ __launch_bounds__(256) void conv_planes_k(
    const float* __restrict__ src, short* __restrict__ hi, short* __restrict__ lo)
{
    const long i8 = (long)blockIdx.x * 256 + threadIdx.x;
    float4 x = ((const float4*)src)[i8 * 2];
    float4 y = ((const float4*)src)[i8 * 2 + 1];
    uint4 H, L; cvt8(x, y, H, L);
    ((uint4*)hi)[i8] = H; ((uint4*)lo)[i8] = L;
}

// wcat[n][k] = k<1024 ? w_ih1[n][k] : w_hh1[n][k-1024]  (3072 x 2048)
__global__ __launch_bounds__(256) void conv_cat_k(
    const float* __restrict__ wih1, const float* __restrict__ whh1,
    short* __restrict__ hi, short* __restrict__ lo)
{
    const long i8 = (long)blockIdx.x * 256 + threadIdx.x;
    const int k8 = (int)(i8 & 255);
    const long row = i8 >> 8;
    const int k = k8 * 8;
    const float* s = (k < 1024) ? (wih1 + row * 1024 + k) : (whh1 + row * 1024 + (k - 1024));
    float4 x = ((const float4*)s)[0];
    float4 y = ((const float4*)s)[1];
    uint4 H, L; cvt8(x, y, H, L);
    ((uint4*)hi)[i8] = H; ((uint4*)lo)[i8] = L;
}

// gathered embedding rows -> planes (8192 x 1024)
__global__ __launch_bounds__(256) void conv_gather_k(
    const float* __restrict__ emb, const int* __restrict__ input,
    short* __restrict__ hi, short* __restrict__ lo)
{
    const long i8 = (long)blockIdx.x * 256 + threadIdx.x;
    const int c8 = (int)(i8 & 127);
    const long row = i8 >> 7;
    const float* s = emb + (size_t)input[row] * 1024 + c8 * 8;
    float4 x = ((const float4*)s)[0];
    float4 y = ((const float4*)s)[1];
    uint4 H, L; cvt8(x, y, H, L);
    ((uint4*)hi)[i8] = H; ((uint4*)lo)[i8] = L;
}

// ============== big batched GEMM: 128x128 block tile ==============
template<int MODE, bool CONCAT>
__global__ __launch_bounds__(256, 2) void gemm_big(
    const short* __restrict__ A1h, const short* __restrict__ A1l,
    const short* __restrict__ A2h, const short* __restrict__ A2l,
    const short* __restrict__ Wh,  const short* __restrict__ Wl,
    int K, int nn,
    const float* __restrict__ bias,
    float* __restrict__ outf, short* __restrict__ outh, short* __restrict__ outl,
    int ldo)
{
    extern __shared__ short sm[];
    short* Asm = sm;
    short* Wsm = sm + 16384;
    const int tid = threadIdx.x;
    const int wv = tid >> 6, l = tid & 63;
    const int mq = wv >> 1, nq = wv & 1;
    const int gl = l >> 4, r16 = l & 15;

    const int cpx = gridDim.x >> 3;
    const int id = blockIdx.x;
    const int swz = (id & 7) * cpx + (id >> 3);
    const int bm = swz / nn, bn = swz % nn;
    const long Rbase = (long)bm * 128;
    const int  Cbase = bn * 128;

    const int lda = CONCAT ? (K >> 1) : K;
    const int NC = K >> 5;
    const int NCh = NC >> 1;

    const short *aP1[4], *aP2[4], *wP[4];
    int slda[4];
    #pragma unroll
    for (int j = 0; j < 4; ++j) {
        const int s = tid + j * 256;
        const int pl = s >> 9, sp = s & 511;
        const int row = ((sp >> 6) << 4) | (sp & 15);
        const int kg = (sp >> 4) & 3;
        slda[j] = s * 8;
        const short* a1 = pl ? A1l : A1h;
        aP1[j] = a1 + (Rbase + row) * (long)lda + kg * 8;
        if (CONCAT) {
            const short* a2 = pl ? A2l : A2h;
            aP2[j] = a2 + (Rbase + row) * (long)lda + kg * 8;
        } else aP2[j] = aP1[j];
        const short* wp = pl ? Wl : Wh;
        wP[j] = wp + ((long)Cbase + row) * (long)K + kg * 8;
    }

    f32x4 acc[4][4];
    #pragma unroll
    for (int i = 0; i < 4; ++i)
        #pragma unroll
        for (int j = 0; j < 4; ++j) acc[i][j] = (f32x4)0.f;

    short8 rA[4], rW[4];
    auto LOADC = [&](int c) {
        const bool p1 = !CONCAT || (c < NCh);
        const long ko = p1 ? (long)c * 32 : (long)c * 32 - (K >> 1);
        #pragma unroll
        for (int j = 0; j < 4; ++j) {
            rA[j] = *(const short8*)((p1 ? aP1[j] : aP2[j]) + ko);
            rW[j] = *(const short8*)(wP[j] + (long)c * 32);
        }
    };
    auto STORE = [&](int c) {
        const int b = (c & 1) << 13;
        #pragma unroll
        for (int j = 0; j < 4; ++j) {
            *(short8*)(Asm + b + slda[j]) = rA[j];
            *(short8*)(Wsm + b + slda[j]) = rW[j];
        }
    };

    LOADC(0); STORE(0); LOADC(1);
    __syncthreads();

    for (int c = 0; c < NC; ++c) {
        const int b = (c & 1) << 13;
        short8 ah[4], al[4], wh[4], wl[4];
        #pragma unroll
        for (int f = 0; f < 4; ++f) {
            const short* ab = Asm + b + ((mq * 4 + f) * 64 + l) * 8;
            ah[f] = *(const short8*)ab;
            al[f] = *(const short8*)(ab + 4096);
            const short* wb = Wsm + b + ((nq * 4 + f) * 64 + l) * 8;
            wh[f] = *(const short8*)wb;
            wl[f] = *(const short8*)(wb + 4096);
        }
        if (c + 1 < NC) STORE(c + 1);
        if (c + 2 < NC) LOADC(c + 2);
        #pragma unroll
        for (int mf = 0; mf < 4; ++mf)
            #pragma unroll
            for (int nf = 0; nf < 4; ++nf) {
                TRI(ah[mf], al[mf], wh[nf], wl[nf], acc[mf][nf]);
            }
        __syncthreads();
    }

    #pragma unroll
    for (int mf = 0; mf < 4; ++mf) {
        #pragma unroll
        for (int reg = 0; reg < 4; ++reg) {
            const long R = Rbase + mq * 64 + mf * 16 + gl * 4 + reg;
            #pragma unroll
            for (int nf = 0; nf < 4; ++nf) {
                const int col = Cbase + nq * 64 + nf * 16 + r16;
                const float v = acc[mf][nf][reg];
                if constexpr (MODE == 0) {
                    outf[R * (long)ldo + col] = v + bias[col];
                } else if constexpr (MODE == 1) {
                    const unsigned short hi = f2bf(v), lo = f2bf(v - bf2f(hi));
                    outh[R * (long)ldo + col] = (short)hi;
                    outl[R * (long)ldo + col] = (short)lo;
                } else {
                    outf[R * (long)ldo + col] = tanhf(v);
                }
            }
        }
    }
}

// ============== recurrence GEMM core (device fn, gate epilogue) ==============
// MODE 2: layer-0 gate: other = gi0_t (f32, H3 stride), bias = b_hh0. WLO.
// MODE 3: concat gate (layer 1): acc{r,z,ni,nh}; first K-half (w_ih1) full
//         TRI, second half (w_hh1) WLO — numerics identical to R5.
template<int P, int MODE, bool CONCAT, bool WLO>
__device__ __forceinline__ void gemm_core(
    const short* __restrict__ A1h, const short* __restrict__ A1l,
    const short* __restrict__ A2h, const short* __restrict__ A2l,
    const short* __restrict__ Wh,  const short* __restrict__ Wl,
    int K,
    const float* __restrict__ bias, const float* __restrict__ bias2,
    const float* __restrict__ other, const float* __restrict__ hprev,
    float* __restrict__ outf, short* __restrict__ outh, short* __restrict__ outl)
{
    extern __shared__ short sm[];
    const int ABUF = 8192, WBUF = P * 2048;
    short* Asm = sm;
    short* Wsm = sm + 2 * ABUF;
    const int tid = threadIdx.x;
    const int wv = tid >> 6, l = tid & 63;
    const int gl = l >> 4, r16 = l & 15;
    const int bm = blockIdx.x, bj = blockIdx.y;

    const int NC = K >> 6;
    const int NC_half = NC >> 1;

    const short *a1hP[2], *a1lP[2], *a2hP[2], *a2lP[2];
    int aLds[2];
    const int ldA = CONCAT ? (K >> 1) : K;
    #pragma unroll
    for (int i = 0; i < 2; ++i) {
        const int s = tid + i * 256;
        const int row = ((s >> 6) & 3) * 16 + (s & 15);
        const int kg  = ((s >> 8) << 2) | ((s >> 4) & 3);
        const long r = (long)bm * 64 + row;
        a1hP[i] = A1h + r * ldA + kg * 8;
        a1lP[i] = A1l + r * ldA + kg * 8;
        if (CONCAT) {
            a2hP[i] = A2h + r * (K >> 1) + kg * 8;
            a2lP[i] = A2l + r * (K >> 1) + kg * 8;
        } else { a2hP[i] = a1hP[i]; a2lP[i] = a1lP[i]; }
        aLds[i] = s * 8;
    }
    const bool doW = tid < P * 64;
    const short *whP[2], *wlP[2];
    int wLds[2] = {0, 0};
    if (doW) {
        #pragma unroll
        for (int i = 0; i < 2; ++i) {
            const int s = tid + i * P * 64;
            const int kcw = s / (P * 64);
            const int rem = s - kcw * (P * 64);
            const int p = rem >> 6, ll = rem & 63;
            const int jr = ll & 15, g = ll >> 4;
            const int kg = kcw * 4 + g;
            const long grow = (long)(p << 10) + bj * 16 + jr;
            whP[i] = Wh + grow * K + kg * 8;
            wlP[i] = Wl + grow * K + kg * 8;
            wLds[i] = s * 8;
        }
    }

    constexpr int NACC = (MODE == 3) ? 4 : P;
    f32x4 acc[NACC];
    #pragma unroll
    for (int i = 0; i < NACC; ++i) acc[i] = (f32x4)0.f;

    // whether the W lo plane is needed for chunk c
    auto wloNeed = [&](int c) -> bool {
        if (!WLO) return true;
        if (MODE == 3) return c < NC_half;
        return false;
    };

    short8 rAh[2], rAl[2], rWh[2], rWl[2];
    auto LOADC = [&](int c) {
        const bool part1 = !CONCAT || (c < NC_half);
        const long ko = part1 ? (long)c * 64 : (long)c * 64 - (K >> 1);
        #pragma unroll
        for (int i = 0; i < 2; ++i) {
            rAh[i] = *(const short8*)((part1 ? a1hP[i] : a2hP[i]) + ko);
            rAl[i] = *(const short8*)((part1 ? a1lP[i] : a2lP[i]) + ko);
        }
        if (doW) {
            const bool wl = wloNeed(c);
            #pragma unroll
            for (int i = 0; i < 2; ++i) {
                rWh[i] = *(const short8*)(whP[i] + (long)c * 64);
                if (wl) rWl[i] = *(const short8*)(wlP[i] + (long)c * 64);
            }
        }
    };
    auto STORE = [&](int c) {
        const int b = c & 1;
        #pragma unroll
        for (int i = 0; i < 2; ++i) {
            *(short8*)(Asm + b * ABUF + aLds[i]) = rAh[i];
            *(short8*)(Asm + b * ABUF + 4096 + aLds[i]) = rAl[i];
        }
        if (doW) {
            const bool wl = wloNeed(c);
            #pragma unroll
            for (int i = 0; i < 2; ++i) {
                *(short8*)(Wsm + b * WBUF + wLds[i]) = rWh[i];
                if (wl) *(short8*)(Wsm + b * WBUF + P * 1024 + wLds[i]) = rWl[i];
            }
        }
    };

    LOADC(0); STORE(0); LOADC(1);
    __syncthreads();

    for (int c = 0; c < NC; ++c) {
        const int b = c & 1;
        const bool wl = wloNeed(c);
        short8 fah[2], fal[2], fwh[2][P], fwl[2][P];
        #pragma unroll
        for (int kc = 0; kc < 2; ++kc) {
            const short* ab = Asm + b * ABUF + (kc * 256 + wv * 64 + l) * 8;
            fah[kc] = *(const short8*)ab;
            fal[kc] = *(const short8*)(ab + 4096);
            #pragma unroll
            for (int p = 0; p < P; ++p) {
                const short* wb = Wsm + b * WBUF + (kc * (P * 64) + p * 64 + l) * 8;
                fwh[kc][p] = *(const short8*)wb;
                if (wl) fwl[kc][p] = *(const short8*)(wb + P * 1024);
            }
        }
        if (c + 1 < NC) STORE(c + 1);
        if (c + 2 < NC) LOADC(c + 2);
        #pragma unroll
        for (int kc = 0; kc < 2; ++kc) {
            if constexpr (MODE == 3) {
                if (c < NC_half) {
                    TRI(fah[kc], fal[kc], fwh[kc][0], fwl[kc][0], acc[0]);
                    TRI(fah[kc], fal[kc], fwh[kc][1], fwl[kc][1], acc[1]);
                    TRI(fah[kc], fal[kc], fwh[kc][2], fwl[kc][2], acc[2]);
                } else {
                    DUO(fah[kc], fal[kc], fwh[kc][0], acc[0]);
                    DUO(fah[kc], fal[kc], fwh[kc][1], acc[1]);
                    DUO(fah[kc], fal[kc], fwh[kc][2], acc[3]);
                }
            } else if constexpr (WLO) {
                #pragma unroll
                for (int p = 0; p < P; ++p) { DUO(fah[kc], fal[kc], fwh[kc][p], acc[p]); }
            } else {
                #pragma unroll
                for (int p = 0; p < P; ++p) { TRI(fah[kc], fal[kc], fwh[kc][p], fwl[kc][p], acc[p]); }
            }
        }
        __syncthreads();
    }

    const int jc = bj * 16 + r16;
    #pragma unroll
    for (int reg = 0; reg < 4; ++reg) {
        const long R = (long)bm * 64 + wv * 16 + gl * 4 + reg;
        if constexpr (MODE == 2) {
            const float* orow = other + R * H3;
            const float rr = sigf(orow[jc] + acc[0][reg] + bias[jc]);
            const float zz = sigf(orow[HID + jc] + acc[1][reg] + bias[HID + jc]);
            const float nn = tanhf(orow[2 * HID + jc] + rr * (acc[2][reg] + bias[2 * HID + jc]));
            const float h = (1.f - zz) * nn + zz * hprev[R * HID + jc];
            outf[R * HID + jc] = h;
            const unsigned short hi = f2bf(h), lo = f2bf(h - bf2f(hi));
            outh[R * HID + jc] = (short)hi; outl[R * HID + jc] = (short)lo;
        } else if constexpr (MODE == 3) {
            const float rr = sigf(acc[0][reg] + bias[jc] + bias2[jc]);
            const float zz = sigf(acc[1][reg] + bias[HID + jc] + bias2[HID + jc]);
            const float nn = tanhf(acc[2][reg] + bias[2 * HID + jc] +
                                   rr * (acc[3][reg] + bias2[2 * HID + jc]));
            const float h = (1.f - zz) * nn + zz * hprev[R * HID + jc];
            outf[R * HID + jc] = h;
            const unsigned short hi = f2bf(h), lo = f2bf(h - bf2f(hi));
            outh[R * HID + jc] = (short)hi; outl[R * HID + jc] = (short)lo;
        }
    }
}

// ============== pipelined step kernel: z=0 -> h0_t, z=1 -> h1_{t-1} ==============
__global__ __launch_bounds__(256) void step_k(
    int t,
    const short* __restrict__ hih, const short* __restrict__ hil,
    const float* __restrict__ h_in,
    const float* __restrict__ gi0,
    const short* __restrict__ whh0h, const short* __restrict__ whh0l,
    const short* __restrict__ wcath, const short* __restrict__ wcatl,
    const float* __restrict__ b_hh0,
    const float* __restrict__ b_ih1, const float* __restrict__ b_hh1,
    float* __restrict__ h0f, short* __restrict__ h0ah, short* __restrict__ h0al,
    float* __restrict__ h1f, short* __restrict__ h1ah, short* __restrict__ h1al)
{
    if (blockIdx.z == 0) {
        if (t >= T_STEPS) return;
        const short* a1h = t ? h0ah + (long)(t - 1) * BH : hih;
        const short* a1l = t ? h0al + (long)(t - 1) * BH : hil;
        const float* hp  = t ? h0f + (long)((t - 1) & 1) * BH : h_in;
        gemm_core<3, 2, false, true>(
            a1h, a1l, nullptr, nullptr, whh0h, whh0l, 1024,
            b_hh0, nullptr, gi0 + (long)t * BATCH * H3, hp,
            h0f + (long)(t & 1) * BH, h0ah + (long)t * BH, h0al + (long)t * BH);
    } else {
        if (t < 1) return;
        const int s = t - 1;
        const short* a1h = h0ah + (long)s * BH;
        const short* a1l = h0al + (long)s * BH;
        const short* a2h = s ? h1ah + (long)(s - 1) * BH : hih + BH;
        const short* a2l = s ? h1al + (long)(s - 1) * BH : hil + BH;
        const float* hp  = s ? h1f + (long)((s - 1) & 1) * BH : h_in + BH;
        gemm_core<3, 3, true, true>(
            a1h, a1l, a2h, a2l, wcath, wcatl, 2048,
            b_ih1, b_hh1, nullptr, hp,
            h1f + (long)(s & 1) * BH, h1ah + (long)s * BH, h1al + (long)s * BH);
    }
}

// ============== batched attention scores + softmax (per b) ==============
__global__ __launch_bounds__(256) void scores_k(
    const short* __restrict__ Qh, const short* __restrict__ Ql,
    const short* __restrict__ Hh, const short* __restrict__ Hl,
    float* __restrict__ Pall)
{
    extern __shared__ short sm[];
    short* Asm = sm;
    short* Wsm = sm + 8192;
    const int b = blockIdx.x, tid = threadIdx.x;
    const int wv = tid >> 6, l = tid & 63;
    const int gl = l >> 4, cc = l & 15;

    const int arow = ((tid >> 6) & 3) * 16 + (tid & 15);
    const int ag   = (tid >> 4) & 3;
    const short* qhp = Qh + ((long)arow * BATCH + b) * HID + ag * 8;
    const short* qlp = Ql + ((long)arow * BATCH + b) * HID + ag * 8;
    const int aLds = tid * 8;

    const short *whp[2], *wlp[2]; int wLds[2];
    #pragma unroll
    for (int i = 0; i < 2; ++i) {
        const int s = tid + i * 256;
        const int srow = ((s >> 6) & 7) * 16 + (s & 15);
        const int sg   = (s >> 4) & 3;
        whp[i] = Hh + ((long)srow * BATCH + b) * HID + sg * 8;
        wlp[i] = Hl + ((long)srow * BATCH + b) * HID + sg * 8;
        wLds[i] = s * 8;
    }

    f32x4 acc[8];
    #pragma unroll
    for (int i = 0; i < 8; ++i) acc[i] = (f32x4)0.f;

    short8 rAh, rAl, rWh[2], rWl[2];
    auto LOADC = [&](int c) {
        rAh = *(const short8*)(qhp + c * 32);
        rAl = *(const short8*)(qlp + c * 32);
        #pragma unroll
        for (int i = 0; i < 2; ++i) {
            rWh[i] = *(const short8*)(whp[i] + c * 32);
            rWl[i] = *(const short8*)(wlp[i] + c * 32);
        }
    };
    auto STORE = [&](int c) {
        const int bb = c & 1;
        *(short8*)(Asm + bb * 4096 + aLds) = rAh;
        *(short8*)(Asm + bb * 4096 + 2048 + aLds) = rAl;
        #pragma unroll
        for (int i = 0; i < 2; ++i) {
            *(short8*)(Wsm + bb * 8192 + wLds[i]) = rWh[i];
            *(short8*)(Wsm + bb * 8192 + 4096 + wLds[i]) = rWl[i];
        }
    };

    LOADC(0); STORE(0); LOADC(1);
    __syncthreads();
    for (int c = 0; c < 32; ++c) {
        const int bb = c & 1;
        const short* abp = Asm + bb * 4096 + (wv * 64 + l) * 8;
        short8 ah = *(const short8*)abp;
        short8 al = *(const short8*)(abp + 2048);
        if (c + 1 < 32) STORE(c + 1);
        if (c + 2 < 32) LOADC(c + 2);
        #pragma unroll
        for (int jt = 0; jt < 8; ++jt) {
            const short* wbp = Wsm + bb * 8192 + (jt * 64 + l) * 8;
            short8 wh = *(const short8*)wbp;
            short8 wl = *(const short8*)(wbp + 4096);
            TRI(ah, al, wh, wl, acc[jt]);
        }
        __syncthreads();
    }

    #pragma unroll
    for (int reg = 0; reg < 4; ++reg) {
        float m = acc[0][reg];
        #pragma unroll
        for (int jt = 1; jt < 8; ++jt) m = fmaxf(m, acc[jt][reg]);
        #pragma unroll
        for (int off = 1; off < 16; off <<= 1) m = fmaxf(m, __shfl_xor(m, off));
        float e[8], ssum = 0.f;
        #pragma unroll
        for (int jt = 0; jt < 8; ++jt) { e[jt] = __expf(acc[jt][reg] - m); ssum += e[jt]; }
        #pragma unroll
        for (int off = 1; off < 16; off <<= 1) ssum += __shfl_xor(ssum, off);
        const float inv = 1.f / ssum;
        const int t = wv * 16 + gl * 4 + reg;
        #pragma unroll
        for (int jt = 0; jt < 8; ++jt)
            Pall[((long)t * BATCH + b) * SLEN + jt * 16 + cc] = e[jt] * inv;
    }
}

// context[t,b,col] = sum_s P[t,s] * H[s,b,col]; writes ctx planes.
__global__ __launch_bounds__(256) void ctx_k(
    const float* __restrict__ Pall, const float* __restrict__ H,
    short* __restrict__ Ch, short* __restrict__ Cl)
{
    __shared__ float Ps[T_STEPS * SLEN];
    const int b = blockIdx.x, ht = blockIdx.y, tid = threadIdx.x;
    for (int i = 0; i < 32; ++i) {
        const int idx = i * 256 + tid;
        const int t = idx >> 7, s = idx & 127;
        Ps[idx] = Pall[((long)t * BATCH + b) * SLEN + s];
    }
    __syncthreads();
    const int col = ht * 256 + tid;
    for (int tg = 0; tg < 4; ++tg) {
        float a[16];
        #pragma unroll
        for (int j = 0; j < 16; ++j) a[j] = 0.f;
        for (int s = 0; s < SLEN; ++s) {
            const float hv = H[((long)s * BATCH + b) * HID + col];
            #pragma unroll
            for (int j = 0; j < 16; ++j)
                a[j] = fmaf(Ps[(tg * 16 + j) * SLEN + s], hv, a[j]);
        }
        #pragma unroll
        for (int j = 0; j < 16; ++j) {
            const long row = (long)(tg * 16 + j) * BATCH + b;
            const unsigned short hi = f2bf(a[j]);
            const unsigned short lo = f2bf(a[j] - bf2f(hi));
            Ch[row * HID + col] = (short)hi;
            Cl[row * HID + col] = (short)lo;
        }
    }
}

// =========================== launch ===========================
extern "C" void kernel_launch(void* const* d_in, const int* in_sizes, int n_in,
                              void* d_out, int out_size, void* d_ws, size_t ws_size,
                              hipStream_t stream)
{
    const int*   input = (const int*)  d_in[0];
    const float* h_in  = (const float*)d_in[1];
    const float* Hbuf  = (const float*)d_in[2];
    const float* emb   = (const float*)d_in[3];
    const float* w_ih  = (const float*)d_in[4];
    const float* w_hh  = (const float*)d_in[5];
    const float* b_ih  = (const float*)d_in[6];
    const float* b_hh  = (const float*)d_in[7];
    const float* L1    = (const float*)d_in[8];
    const float* L2    = (const float*)d_in[9];

    float* out = (float*)d_out;

    char* basep = (char*)d_ws;
    size_t off = 0;
    auto alloc = [&](size_t bytes) -> char* {
        off = (off + 255) & ~(size_t)255;
        char* p = basep + off; off += bytes; return p;
    };
    short* wih0h = (short*)alloc(3072L*1024*2); short* wih0l = (short*)alloc(3072L*1024*2);
    short* whh0h = (short*)alloc(3072L*1024*2); short* whh0l = (short*)alloc(3072L*1024*2);
    short* wcath = (short*)alloc(3072L*2048*2); short* wcatl = (short*)alloc(3072L*2048*2);
    short* l1h   = (short*)alloc(1024L*1024*2); short* l1l   = (short*)alloc(1024L*1024*2);
    short* l2h   = (short*)alloc(1024L*2048*2); short* l2l   = (short*)alloc(1024L*2048*2);
    short* Hh    = (short*)alloc(16777216L*2);  short* Hl    = (short*)alloc(16777216L*2);
    short* hih   = (short*)alloc(262144L*2);    short* hil   = (short*)alloc(262144L*2);
    short* h0ah  = (short*)alloc(8388608L*2);   short* h0al  = (short*)alloc(8388608L*2);
    short* h1ah  = (short*)alloc(8388608L*2);   short* h1al  = (short*)alloc(8388608L*2);
    short* eqh   = (short*)alloc(8388608L*2);   short* eql   = (short*)alloc(8388608L*2);
    float* gi0   = (float*)alloc(25165824L*4);
    float* h0f   = (float*)alloc(524288L*4);    // 2*BH ping-pong
    float* h1f   = (float*)alloc(524288L*4);    // 2*BH ping-pong
    float* Pall  = (float*)alloc(1048576L*4);
    short* ctxh  = (short*)gi0;                 // gi0 dead after step loop
    short* ctxl  = ctxh + 8388608L;

    const dim3 blk(256);
    const size_t SMB = 32768 * sizeof(short);                      // 65536
    const size_t SM3 = (2 * 8192 + 2 * 3 * 2048) * sizeof(short);  // 57344

    // ---- phase 0: plane conversions ----
    conv_planes_k<<<1536, blk, 0, stream>>>(w_ih, wih0h, wih0l);
    conv_planes_k<<<1536, blk, 0, stream>>>(w_hh, whh0h, whh0l);
    conv_cat_k<<<3072, blk, 0, stream>>>(w_ih + (size_t)H3 * EMBD,
                                         w_hh + (size_t)H3 * HID, wcath, wcatl);
    conv_planes_k<<<512,  blk, 0, stream>>>(L1, l1h, l1l);
    conv_planes_k<<<1024, blk, 0, stream>>>(L2, l2h, l2l);
    conv_planes_k<<<8192, blk, 0, stream>>>(Hbuf, Hh, Hl);
    conv_planes_k<<<128,  blk, 0, stream>>>(h_in, hih, hil);
    conv_gather_k<<<4096, blk, 0, stream>>>(emb, input, eqh, eql);

    // gi0_all = E @ w_ih0^T + b_ih0   (8192 x 3072 x 1024)
    gemm_big<0, false><<<dim3(1536), blk, SMB, stream>>>(
        eqh, eql, nullptr, nullptr, wih0h, wih0l, 1024, 24,
        b_ih, gi0, nullptr, nullptr, H3);

    // ---- pipelined recurrence: 65 launches ----
    for (int t = 0; t <= T_STEPS; ++t) {
        step_k<<<dim3(2, 64, 2), blk, SM3, stream>>>(
            t, hih, hil, h_in, gi0, whh0h, whh0l, wcath, wcatl,
            b_hh, b_ih + H3, b_hh + H3,
            h0f, h0ah, h0al, h1f, h1ah, h1al);
    }

    // ---- phase 3: batched attention + output ----
    gemm_big<1, false><<<dim3(512), blk, SMB, stream>>>(
        h1ah, h1al, nullptr, nullptr, l1h, l1l, 1024, 8,
        nullptr, nullptr, eqh, eql, HID);
    scores_k<<<dim3(BATCH), blk, 49152, stream>>>(eqh, eql, Hh, Hl, Pall);
    ctx_k<<<dim3(BATCH, 4), blk, 0, stream>>>(Pall, Hbuf, ctxh, ctxl);
    gemm_big<2, true><<<dim3(512), blk, SMB, stream>>>(
        ctxh, ctxl, h1ah, h1al, l2h, l2l, 2048, 8,
        nullptr, out, nullptr, nullptr, HID);

    hipMemcpyAsync(out + (long)T_STEPS * BH, h0f + BH, (size_t)BH * 4,
                   hipMemcpyDeviceToDevice, stream);
    hipMemcpyAsync(out + (long)T_STEPS * BH + BH, h1f + BH, (size_t)BH * 4,
                   hipMemcpyDeviceToDevice, stream);
}